// Round 1
// baseline (6182.928 us; speedup 1.0000x reference)
//
#include <hip/hip_runtime.h>
#include <math.h>

#define NNODES 50000
#define NEDGES 800000

__device__ __forceinline__ float sigf(float x){ return 1.0f/(1.0f+__expf(-x)); }
__device__ __forceinline__ float tanh_f(float x){
  x = fminf(15.0f, fmaxf(-15.0f, x));
  float e = __expf(-2.0f*x);
  return (1.0f-e)/(1.0f+e);
}

// linkpart[l][d] = bl[d] + sum_{k<64} emb_link[l][k]*Wl[k][d]
__global__ void k_linkpart(const float* __restrict__ emb_link, const float* __restrict__ Wl,
                           const float* __restrict__ bl, float* __restrict__ lp){
  int l = blockIdx.x, d = threadIdx.x;
  float acc = bl[d];
  #pragma unroll 8
  for(int k=0;k<64;k++) acc += emb_link[l*64+k]*Wl[k*128+d];
  lp[l*128+d] = acc;
}

// node_emb = tanh(gather(emb_token,i_token) @ Wc + bc); M=50000 K=300 N=128
__global__ __launch_bounds__(256) void k_node_emb(const int* __restrict__ i_token,
      const float* __restrict__ emb_token, const float* __restrict__ Wc,
      const float* __restrict__ bc, float* __restrict__ out){
  __shared__ float As[64][61];
  __shared__ float Wt[60][128];
  __shared__ int rowidx[64];
  int t = threadIdx.x;
  int m0 = blockIdx.x*64;
  if(t<64){ int m = m0+t; rowidx[t] = (m<NNODES)? i_token[m] : 0; }
  int cg = t & 15, rg = t >> 4;
  float acc[4][8];
  float4 b0 = *(const float4*)(bc + cg*8);
  float4 b1 = *(const float4*)(bc + cg*8+4);
  #pragma unroll
  for(int r=0;r<4;r++){
    acc[r][0]=b0.x; acc[r][1]=b0.y; acc[r][2]=b0.z; acc[r][3]=b0.w;
    acc[r][4]=b1.x; acc[r][5]=b1.y; acc[r][6]=b1.z; acc[r][7]=b1.w;
  }
  __syncthreads();
  for(int kt=0; kt<5; kt++){
    #pragma unroll
    for(int j=0;j<15;j++){
      int idx = t + j*256;
      int r = idx/60, k = idx - r*60;
      As[r][k] = emb_token[(size_t)rowidx[r]*300 + kt*60 + k];
    }
    #pragma unroll
    for(int j=0;j<30;j++){
      int idx = t + j*256;
      int k = idx >> 7, c = idx & 127;
      Wt[k][c] = Wc[(size_t)(kt*60+k)*128 + c];
    }
    __syncthreads();
    #pragma unroll 4
    for(int k=0;k<60;k++){
      float4 w0 = *(const float4*)&Wt[k][cg*8];
      float4 w1 = *(const float4*)&Wt[k][cg*8+4];
      #pragma unroll
      for(int r=0;r<4;r++){
        float a = As[rg*4+r][k];
        acc[r][0] += a*w0.x; acc[r][1] += a*w0.y; acc[r][2] += a*w0.z; acc[r][3] += a*w0.w;
        acc[r][4] += a*w1.x; acc[r][5] += a*w1.y; acc[r][6] += a*w1.z; acc[r][7] += a*w1.w;
      }
    }
    __syncthreads();
  }
  #pragma unroll
  for(int r=0;r<4;r++){
    int m = m0 + rg*4 + r;
    if(m < NNODES){
      float4 o0 = make_float4(tanh_f(acc[r][0]),tanh_f(acc[r][1]),tanh_f(acc[r][2]),tanh_f(acc[r][3]));
      float4 o1 = make_float4(tanh_f(acc[r][4]),tanh_f(acc[r][5]),tanh_f(acc[r][6]),tanh_f(acc[r][7]));
      *(float4*)(out + (size_t)m*128 + cg*8)     = o0;
      *(float4*)(out + (size_t)m*128 + cg*8 + 4) = o1;
    }
  }
}

// C[m][n] = (bias?bias[n]:0) + sum_p Apart_p[m][:] @ W[p*128+k][n]; M=50000, N=128
__global__ __launch_bounds__(256) void k_gemm(
      const float* __restrict__ A0, const float* __restrict__ A1,
      const float* __restrict__ A2, const float* __restrict__ A3,
      int nparts, const float* __restrict__ W, const float* __restrict__ bias,
      float* __restrict__ C){
  __shared__ float As[64][33];
  __shared__ float Wt[32][128];
  int t = threadIdx.x;
  int m0 = blockIdx.x*64;
  int cg = t & 15, rg = t >> 4;
  float acc[4][8];
  if(bias){
    float4 b0 = *(const float4*)(bias + cg*8);
    float4 b1 = *(const float4*)(bias + cg*8+4);
    #pragma unroll
    for(int r=0;r<4;r++){
      acc[r][0]=b0.x; acc[r][1]=b0.y; acc[r][2]=b0.z; acc[r][3]=b0.w;
      acc[r][4]=b1.x; acc[r][5]=b1.y; acc[r][6]=b1.z; acc[r][7]=b1.w;
    }
  } else {
    #pragma unroll
    for(int r=0;r<4;r++)
      #pragma unroll
      for(int j=0;j<8;j++) acc[r][j]=0.f;
  }
  for(int p=0;p<nparts;p++){
    const float* Ap = (p==0)?A0:(p==1)?A1:(p==2)?A2:A3;
    for(int kt=0;kt<4;kt++){
      #pragma unroll
      for(int j=0;j<2;j++){
        int f4 = t + j*256;
        int r = f4 >> 3, c4 = f4 & 7;
        int m = m0 + r; if(m >= NNODES) m = NNODES-1;
        float4 v = *(const float4*)(Ap + (size_t)m*128 + kt*32 + c4*4);
        As[r][c4*4+0]=v.x; As[r][c4*4+1]=v.y; As[r][c4*4+2]=v.z; As[r][c4*4+3]=v.w;
      }
      #pragma unroll
      for(int j=0;j<4;j++){
        int f4 = t + j*256;
        int k = f4 >> 5, c4 = f4 & 31;
        float4 v = *(const float4*)(W + (size_t)(p*128 + kt*32 + k)*128 + c4*4);
        *(float4*)&Wt[k][c4*4] = v;
      }
      __syncthreads();
      #pragma unroll 4
      for(int k=0;k<32;k++){
        float4 w0 = *(const float4*)&Wt[k][cg*8];
        float4 w1 = *(const float4*)&Wt[k][cg*8+4];
        #pragma unroll
        for(int r=0;r<4;r++){
          float a = As[rg*4+r][k];
          acc[r][0] += a*w0.x; acc[r][1] += a*w0.y; acc[r][2] += a*w0.z; acc[r][3] += a*w0.w;
          acc[r][4] += a*w1.x; acc[r][5] += a*w1.y; acc[r][6] += a*w1.z; acc[r][7] += a*w1.w;
        }
      }
      __syncthreads();
    }
  }
  #pragma unroll
  for(int r=0;r<4;r++){
    int m = m0 + rg*4 + r;
    if(m < NNODES){
      *(float4*)(C + (size_t)m*128 + cg*8)     = make_float4(acc[r][0],acc[r][1],acc[r][2],acc[r][3]);
      *(float4*)(C + (size_t)m*128 + cg*8 + 4) = make_float4(acc[r][4],acc[r][5],acc[r][6],acc[r][7]);
    }
  }
}

// per edge: v = tanh(linkpart[i_link] + nodepart[i_from]); x_in[i_to]+=v; x_out[i_from]+=v
__global__ void k_edge_x(const int* __restrict__ i_link, const int* __restrict__ i_from,
                         const int* __restrict__ i_to, const float* __restrict__ lp,
                         const float* __restrict__ npart,
                         float* __restrict__ x_in, float* __restrict__ x_out){
  int g = blockIdx.x*256 + threadIdx.x;
  int e = g >> 5, lane = g & 31;
  if(e >= NEDGES) return;
  int il = i_link[e], ifr = i_from[e], ito = i_to[e];
  int c = lane*4;
  float4 a = *(const float4*)(lp + il*128 + c);
  float4 b = *(const float4*)(npart + (size_t)ifr*128 + c);
  float vx = tanh_f(a.x+b.x), vy = tanh_f(a.y+b.y), vz = tanh_f(a.z+b.z), vw = tanh_f(a.w+b.w);
  float* pi = x_in + (size_t)ito*128 + c;
  atomicAdd(pi+0,vx); atomicAdd(pi+1,vy); atomicAdd(pi+2,vz); atomicAdd(pi+3,vw);
  float* po = x_out + (size_t)ifr*128 + c;
  atomicAdd(po+0,vx); atomicAdd(po+1,vy); atomicAdd(po+2,vz); atomicAdd(po+3,vw);
}

// per edge: h_in[i_to]+=h[i_from]; h_out[i_from]+=h[i_to]
__global__ void k_edge_h(const int* __restrict__ i_from, const int* __restrict__ i_to,
                         const float* __restrict__ h,
                         float* __restrict__ h_in, float* __restrict__ h_out){
  int g = blockIdx.x*256 + threadIdx.x;
  int e = g >> 5, lane = g & 31;
  if(e >= NEDGES) return;
  int ifr = i_from[e], ito = i_to[e];
  int c = lane*4;
  float4 a = *(const float4*)(h + (size_t)ifr*128 + c);
  float* pi = h_in + (size_t)ito*128 + c;
  atomicAdd(pi+0,a.x); atomicAdd(pi+1,a.y); atomicAdd(pi+2,a.z); atomicAdd(pi+3,a.w);
  float4 b = *(const float4*)(h + (size_t)ito*128 + c);
  float* po = h_out + (size_t)ifr*128 + c;
  atomicAdd(po+0,b.x); atomicAdd(po+1,b.y); atomicAdd(po+2,b.z); atomicAdd(po+3,b.w);
}

// layer1: c1 = sig(pi)*tanh(pu); h1 = sig(po)*tanh(c1)
__global__ void k_layer1(const float* __restrict__ pi, const float* __restrict__ po,
                         const float* __restrict__ pu,
                         float* __restrict__ c1, float* __restrict__ h1){
  size_t i = (size_t)(blockIdx.x*256 + threadIdx.x)*4;
  float4 vi = *(const float4*)(pi+i);
  float4 vo = *(const float4*)(po+i);
  float4 vu = *(const float4*)(pu+i);
  float4 c, h;
  c.x = sigf(vi.x)*tanh_f(vu.x); c.y = sigf(vi.y)*tanh_f(vu.y);
  c.z = sigf(vi.z)*tanh_f(vu.z); c.w = sigf(vi.w)*tanh_f(vu.w);
  h.x = sigf(vo.x)*tanh_f(c.x); h.y = sigf(vo.y)*tanh_f(c.y);
  h.z = sigf(vo.z)*tanh_f(c.z); h.w = sigf(vo.w)*tanh_f(c.w);
  *(float4*)(c1+i) = c;
  *(float4*)(h1+i) = h;
}

// layer2: c2 = sig(pf)*c1 + sig(pi)*tanh(pu); out = sig(po)*tanh(c2)   (pu may alias out)
__global__ void k_layer2(const float* __restrict__ pi, const float* __restrict__ po,
                         const float* __restrict__ pf, const float* pu,
                         const float* __restrict__ c1, float* out){
  size_t i = (size_t)(blockIdx.x*256 + threadIdx.x)*4;
  float4 vi = *(const float4*)(pi+i);
  float4 vo = *(const float4*)(po+i);
  float4 vf = *(const float4*)(pf+i);
  float4 vu = *(const float4*)(pu+i);
  float4 vc = *(const float4*)(c1+i);
  float4 h;
  float cx = sigf(vf.x)*vc.x + sigf(vi.x)*tanh_f(vu.x);
  float cy = sigf(vf.y)*vc.y + sigf(vi.y)*tanh_f(vu.y);
  float cz = sigf(vf.z)*vc.z + sigf(vi.z)*tanh_f(vu.z);
  float cw = sigf(vf.w)*vc.w + sigf(vi.w)*tanh_f(vu.w);
  h.x = sigf(vo.x)*tanh_f(cx); h.y = sigf(vo.y)*tanh_f(cy);
  h.z = sigf(vo.z)*tanh_f(cz); h.w = sigf(vo.w)*tanh_f(cw);
  *(float4*)(out+i) = h;
}

extern "C" void kernel_launch(void* const* d_in, const int* in_sizes, int n_in,
                              void* d_out, int out_size, void* d_ws, size_t ws_size,
                              hipStream_t stream){
  const int*   i_token  = (const int*)d_in[0];
  const int*   i_link   = (const int*)d_in[1];
  const int*   i_from   = (const int*)d_in[2];
  const int*   i_to     = (const int*)d_in[3];
  const float* emb_token= (const float*)d_in[4];
  const float* emb_link = (const float*)d_in[5];
  const float* Wc = (const float*)d_in[6];  const float* bc = (const float*)d_in[7];
  const float* Wl = (const float*)d_in[8];  const float* bl = (const float*)d_in[9];
  const float* Wi = (const float*)d_in[10]; const float* bi = (const float*)d_in[11];
  const float* Wo = (const float*)d_in[12]; const float* bo = (const float*)d_in[13];
  const float* Wf = (const float*)d_in[14]; const float* bf_ = (const float*)d_in[15];
  const float* Wu = (const float*)d_in[16]; const float* bu = (const float*)d_in[17];
  float* out = (float*)d_out;

  const size_t NB = (size_t)NNODES*128;
  float* ws  = (float*)d_ws;
  float* bufA = ws + 0*NB;  // node_emb -> pre_i
  float* bufB = ws + 1*NB;  // nodepart -> pre_o
  float* bufC = ws + 2*NB;  // x_in
  float* bufD = ws + 3*NB;  // x_out
  float* bufE = ws + 4*NB;  // h_in
  float* bufF = ws + 5*NB;  // h_out
  float* bufG = ws + 6*NB;  // c1
  float* bufH = ws + 7*NB;  // pre_u (L1) / pre_f (L2)
  float* linkpart = ws + 8*NB;

  const int GB = (NNODES + 63)/64;  // 782

  k_linkpart<<<50,128,0,stream>>>(emb_link, Wl, bl, linkpart);
  k_node_emb<<<GB,256,0,stream>>>(i_token, emb_token, Wc, bc, bufA);
  // nodepart = node_emb @ Wl[64:192]
  k_gemm<<<GB,256,0,stream>>>(bufA,nullptr,nullptr,nullptr,1, Wl + 64*128, nullptr, bufB);
  hipMemsetAsync(bufC, 0, NB*sizeof(float), stream);
  hipMemsetAsync(bufD, 0, NB*sizeof(float), stream);
  k_edge_x<<<NEDGES/8,256,0,stream>>>(i_link,i_from,i_to,linkpart,bufB,bufC,bufD);
  // layer-1 gate preacts (h=0 -> only rows 0..255 of W; fg unused since c=0)
  k_gemm<<<GB,256,0,stream>>>(bufC,bufD,nullptr,nullptr,2, Wi, bi, bufA);
  k_gemm<<<GB,256,0,stream>>>(bufC,bufD,nullptr,nullptr,2, Wo, bo, bufB);
  k_gemm<<<GB,256,0,stream>>>(bufC,bufD,nullptr,nullptr,2, Wu, bu, bufH);
  k_layer1<<<(int)(NB/4/256),256,0,stream>>>(bufA,bufB,bufH,bufG,out);
  hipMemsetAsync(bufE, 0, NB*sizeof(float), stream);
  hipMemsetAsync(bufF, 0, NB*sizeof(float), stream);
  k_edge_h<<<NEDGES/8,256,0,stream>>>(i_from,i_to,out,bufE,bufF);
  // layer-2 gate preacts
  k_gemm<<<GB,256,0,stream>>>(bufC,bufD,bufE,bufF,4, Wi, bi, bufA);
  k_gemm<<<GB,256,0,stream>>>(bufC,bufD,bufE,bufF,4, Wo, bo, bufB);
  k_gemm<<<GB,256,0,stream>>>(bufC,bufD,bufE,bufF,4, Wf, bf_, bufH);
  k_gemm<<<GB,256,0,stream>>>(bufC,bufD,bufE,bufF,4, Wu, bu, out);
  k_layer2<<<(int)(NB/4/256),256,0,stream>>>(bufA,bufB,bufH,out,bufG,out);
}

// Round 2
// 1362.141 us; speedup vs baseline: 4.5391x; 4.5391x over previous
//
#include <hip/hip_runtime.h>
#include <math.h>

#define NNODES 50000
#define NEDGES 800000

__device__ __forceinline__ float sigf(float x){ return 1.0f/(1.0f+__expf(-x)); }
__device__ __forceinline__ float tanh_f(float x){
  x = fminf(15.0f, fmaxf(-15.0f, x));
  float e = __expf(-2.0f*x);
  return (1.0f-e)/(1.0f+e);
}

// linkpart[l][d] = bl[d] + sum_{k<64} emb_link[l][k]*Wl[k][d]
__global__ void k_linkpart(const float* __restrict__ emb_link, const float* __restrict__ Wl,
                           const float* __restrict__ bl, float* __restrict__ lp){
  int l = blockIdx.x, d = threadIdx.x;
  float acc = bl[d];
  #pragma unroll 8
  for(int k=0;k<64;k++) acc += emb_link[l*64+k]*Wl[k*128+d];
  lp[l*128+d] = acc;
}

// node_emb = tanh(gather(emb_token,i_token) @ Wc + bc); M=50000 K=300 N=128
__global__ __launch_bounds__(256) void k_node_emb(const int* __restrict__ i_token,
      const float* __restrict__ emb_token, const float* __restrict__ Wc,
      const float* __restrict__ bc, float* __restrict__ out){
  __shared__ float As[64][61];
  __shared__ float Wt[60][128];
  __shared__ int rowidx[64];
  int t = threadIdx.x;
  int m0 = blockIdx.x*64;
  if(t<64){ int m = m0+t; rowidx[t] = (m<NNODES)? i_token[m] : 0; }
  int cg = t & 15, rg = t >> 4;
  float acc[4][8];
  float4 b0 = *(const float4*)(bc + cg*8);
  float4 b1 = *(const float4*)(bc + cg*8+4);
  #pragma unroll
  for(int r=0;r<4;r++){
    acc[r][0]=b0.x; acc[r][1]=b0.y; acc[r][2]=b0.z; acc[r][3]=b0.w;
    acc[r][4]=b1.x; acc[r][5]=b1.y; acc[r][6]=b1.z; acc[r][7]=b1.w;
  }
  __syncthreads();
  for(int kt=0; kt<5; kt++){
    #pragma unroll
    for(int j=0;j<15;j++){
      int idx = t + j*256;
      int r = idx/60, k = idx - r*60;
      As[r][k] = emb_token[(size_t)rowidx[r]*300 + kt*60 + k];
    }
    #pragma unroll
    for(int j=0;j<30;j++){
      int idx = t + j*256;
      int k = idx >> 7, c = idx & 127;
      Wt[k][c] = Wc[(size_t)(kt*60+k)*128 + c];
    }
    __syncthreads();
    #pragma unroll 4
    for(int k=0;k<60;k++){
      float4 w0 = *(const float4*)&Wt[k][cg*8];
      float4 w1 = *(const float4*)&Wt[k][cg*8+4];
      #pragma unroll
      for(int r=0;r<4;r++){
        float a = As[rg*4+r][k];
        acc[r][0] += a*w0.x; acc[r][1] += a*w0.y; acc[r][2] += a*w0.z; acc[r][3] += a*w0.w;
        acc[r][4] += a*w1.x; acc[r][5] += a*w1.y; acc[r][6] += a*w1.z; acc[r][7] += a*w1.w;
      }
    }
    __syncthreads();
  }
  #pragma unroll
  for(int r=0;r<4;r++){
    int m = m0 + rg*4 + r;
    if(m < NNODES){
      float4 o0 = make_float4(tanh_f(acc[r][0]),tanh_f(acc[r][1]),tanh_f(acc[r][2]),tanh_f(acc[r][3]));
      float4 o1 = make_float4(tanh_f(acc[r][4]),tanh_f(acc[r][5]),tanh_f(acc[r][6]),tanh_f(acc[r][7]));
      *(float4*)(out + (size_t)m*128 + cg*8)     = o0;
      *(float4*)(out + (size_t)m*128 + cg*8 + 4) = o1;
    }
  }
}

// C[m][n] = (bias?bias[n]:0) + sum_p Apart_p[m][:] @ W[p*128+k][n]; M=50000, N=128
__global__ __launch_bounds__(256) void k_gemm(
      const float* __restrict__ A0, const float* __restrict__ A1,
      const float* __restrict__ A2, const float* __restrict__ A3,
      int nparts, const float* __restrict__ W, const float* __restrict__ bias,
      float* __restrict__ C){
  __shared__ float As[64][33];
  __shared__ float Wt[32][128];
  int t = threadIdx.x;
  int m0 = blockIdx.x*64;
  int cg = t & 15, rg = t >> 4;
  float acc[4][8];
  if(bias){
    float4 b0 = *(const float4*)(bias + cg*8);
    float4 b1 = *(const float4*)(bias + cg*8+4);
    #pragma unroll
    for(int r=0;r<4;r++){
      acc[r][0]=b0.x; acc[r][1]=b0.y; acc[r][2]=b0.z; acc[r][3]=b0.w;
      acc[r][4]=b1.x; acc[r][5]=b1.y; acc[r][6]=b1.z; acc[r][7]=b1.w;
    }
  } else {
    #pragma unroll
    for(int r=0;r<4;r++)
      #pragma unroll
      for(int j=0;j<8;j++) acc[r][j]=0.f;
  }
  for(int p=0;p<nparts;p++){
    const float* Ap = (p==0)?A0:(p==1)?A1:(p==2)?A2:A3;
    for(int kt=0;kt<4;kt++){
      #pragma unroll
      for(int j=0;j<2;j++){
        int f4 = t + j*256;
        int r = f4 >> 3, c4 = f4 & 7;
        int m = m0 + r; if(m >= NNODES) m = NNODES-1;
        float4 v = *(const float4*)(Ap + (size_t)m*128 + kt*32 + c4*4);
        As[r][c4*4+0]=v.x; As[r][c4*4+1]=v.y; As[r][c4*4+2]=v.z; As[r][c4*4+3]=v.w;
      }
      #pragma unroll
      for(int j=0;j<4;j++){
        int f4 = t + j*256;
        int k = f4 >> 5, c4 = f4 & 31;
        float4 v = *(const float4*)(W + (size_t)(p*128 + kt*32 + k)*128 + c4*4);
        *(float4*)&Wt[k][c4*4] = v;
      }
      __syncthreads();
      #pragma unroll 4
      for(int k=0;k<32;k++){
        float4 w0 = *(const float4*)&Wt[k][cg*8];
        float4 w1 = *(const float4*)&Wt[k][cg*8+4];
        #pragma unroll
        for(int r=0;r<4;r++){
          float a = As[rg*4+r][k];
          acc[r][0] += a*w0.x; acc[r][1] += a*w0.y; acc[r][2] += a*w0.z; acc[r][3] += a*w0.w;
          acc[r][4] += a*w1.x; acc[r][5] += a*w1.y; acc[r][6] += a*w1.z; acc[r][7] += a*w1.w;
        }
      }
      __syncthreads();
    }
  }
  #pragma unroll
  for(int r=0;r<4;r++){
    int m = m0 + rg*4 + r;
    if(m < NNODES){
      *(float4*)(C + (size_t)m*128 + cg*8)     = make_float4(acc[r][0],acc[r][1],acc[r][2],acc[r][3]);
      *(float4*)(C + (size_t)m*128 + cg*8 + 4) = make_float4(acc[r][4],acc[r][5],acc[r][6],acc[r][7]);
    }
  }
}

// ---------------- CSR build ----------------
__global__ void k_hist(const int* __restrict__ i_to, const int* __restrict__ i_from,
                       int* __restrict__ cnt_to, int* __restrict__ cnt_from){
  int e = blockIdx.x*256 + threadIdx.x;
  if(e >= NEDGES) return;
  atomicAdd(&cnt_to[i_to[e]], 1);
  atomicAdd(&cnt_from[i_from[e]], 1);
}

// exclusive scan of 50000 ints; writes off[] and cur[] (fill cursor)
__global__ __launch_bounds__(256) void k_scan(const int* __restrict__ cnt_to, int* off_to, int* cur_to,
                                              const int* __restrict__ cnt_from, int* off_from, int* cur_from){
  const int* cnt = blockIdx.x ? cnt_from : cnt_to;
  int* off = blockIdx.x ? off_from : off_to;
  int* cur = blockIdx.x ? cur_from : cur_to;
  __shared__ int part[256];
  int t = threadIdx.x;
  const int CH = 196;  // 256*196 = 50176 >= 50000
  int base = t*CH;
  int s = 0;
  for(int i=0;i<CH;i++){ int idx = base+i; if(idx<NNODES) s += cnt[idx]; }
  part[t] = s; __syncthreads();
  for(int d=1; d<256; d<<=1){
    int v = (t>=d) ? part[t-d] : 0;
    __syncthreads();
    part[t] += v;
    __syncthreads();
  }
  int run = (t==0) ? 0 : part[t-1];
  for(int i=0;i<CH;i++){
    int idx = base+i;
    if(idx<NNODES){ off[idx]=run; cur[idx]=run; run += cnt[idx]; }
  }
}

// payload = other_node | (i_link << 16)   (node ids < 50000 < 2^16, link < 50)
__global__ void k_fill(const int* __restrict__ i_link, const int* __restrict__ i_from,
                       const int* __restrict__ i_to,
                       int* __restrict__ cur_to, int* __restrict__ cur_from,
                       int* __restrict__ pay_to, int* __restrict__ pay_from){
  int e = blockIdx.x*256 + threadIdx.x;
  if(e >= NEDGES) return;
  int il = i_link[e], f = i_from[e], tt = i_to[e];
  int p1 = atomicAdd(&cur_to[tt], 1);  pay_to[p1]  = f  | (il<<16);
  int p2 = atomicAdd(&cur_from[f], 1); pay_from[p2] = tt | (il<<16);
}

// ---------------- gathers (one 32-lane group per node, float4 lanes) ----------------
// x_in[v] = sum over incoming edges: tanh(lp[il] + npart[src])
__global__ __launch_bounds__(256) void k_gather_xin(const int* __restrict__ off, const int* __restrict__ end,
      const int* __restrict__ pay, const float* __restrict__ lp,
      const float* __restrict__ npart, float* __restrict__ out){
  int n = blockIdx.x*8 + (threadIdx.x>>5);
  if(n >= NNODES) return;
  int c = (threadIdx.x & 31)*4;
  float4 acc = make_float4(0.f,0.f,0.f,0.f);
  int s = off[n], e = end[n];
  for(int j=s;j<e;j++){
    int p = pay[j];
    int src = p & 0xFFFF, il = p >> 16;
    float4 a = *(const float4*)(lp + il*128 + c);
    float4 b = *(const float4*)(npart + (size_t)src*128 + c);
    acc.x += tanh_f(a.x+b.x); acc.y += tanh_f(a.y+b.y);
    acc.z += tanh_f(a.z+b.z); acc.w += tanh_f(a.w+b.w);
  }
  *(float4*)(out + (size_t)n*128 + c) = acc;
}

// x_out[u] = sum over outgoing edges: tanh(lp[il] + npart[u])  (node part is the key itself)
__global__ __launch_bounds__(256) void k_gather_xout(const int* __restrict__ off, const int* __restrict__ end,
      const int* __restrict__ pay, const float* __restrict__ lp,
      const float* __restrict__ npart, float* __restrict__ out){
  int n = blockIdx.x*8 + (threadIdx.x>>5);
  if(n >= NNODES) return;
  int c = (threadIdx.x & 31)*4;
  float4 b = *(const float4*)(npart + (size_t)n*128 + c);
  float4 acc = make_float4(0.f,0.f,0.f,0.f);
  int s = off[n], e = end[n];
  for(int j=s;j<e;j++){
    int p = pay[j];
    int il = p >> 16;
    float4 a = *(const float4*)(lp + il*128 + c);
    acc.x += tanh_f(a.x+b.x); acc.y += tanh_f(a.y+b.y);
    acc.z += tanh_f(a.z+b.z); acc.w += tanh_f(a.w+b.w);
  }
  *(float4*)(out + (size_t)n*128 + c) = acc;
}

// generic sum-gather: out[n] = sum src[pay[j] & 0xFFFF]
__global__ __launch_bounds__(256) void k_gather_sum(const int* __restrict__ off, const int* __restrict__ end,
      const int* __restrict__ pay, const float* __restrict__ src, float* __restrict__ out){
  int n = blockIdx.x*8 + (threadIdx.x>>5);
  if(n >= NNODES) return;
  int c = (threadIdx.x & 31)*4;
  float4 acc = make_float4(0.f,0.f,0.f,0.f);
  int s = off[n], e = end[n];
  for(int j=s;j<e;j++){
    int v = pay[j] & 0xFFFF;
    float4 a = *(const float4*)(src + (size_t)v*128 + c);
    acc.x += a.x; acc.y += a.y; acc.z += a.z; acc.w += a.w;
  }
  *(float4*)(out + (size_t)n*128 + c) = acc;
}

// layer1: c1 = sig(pi)*tanh(pu); h1 = sig(po)*tanh(c1)
__global__ void k_layer1(const float* __restrict__ pi, const float* __restrict__ po,
                         const float* __restrict__ pu,
                         float* __restrict__ c1, float* __restrict__ h1){
  size_t i = (size_t)(blockIdx.x*256 + threadIdx.x)*4;
  float4 vi = *(const float4*)(pi+i);
  float4 vo = *(const float4*)(po+i);
  float4 vu = *(const float4*)(pu+i);
  float4 c, h;
  c.x = sigf(vi.x)*tanh_f(vu.x); c.y = sigf(vi.y)*tanh_f(vu.y);
  c.z = sigf(vi.z)*tanh_f(vu.z); c.w = sigf(vi.w)*tanh_f(vu.w);
  h.x = sigf(vo.x)*tanh_f(c.x); h.y = sigf(vo.y)*tanh_f(c.y);
  h.z = sigf(vo.z)*tanh_f(c.z); h.w = sigf(vo.w)*tanh_f(c.w);
  *(float4*)(c1+i) = c;
  *(float4*)(h1+i) = h;
}

// layer2: c2 = sig(pf)*c1 + sig(pi)*tanh(pu); out = sig(po)*tanh(c2)   (pu may alias out)
__global__ void k_layer2(const float* __restrict__ pi, const float* __restrict__ po,
                         const float* __restrict__ pf, const float* pu,
                         const float* __restrict__ c1, float* out){
  size_t i = (size_t)(blockIdx.x*256 + threadIdx.x)*4;
  float4 vi = *(const float4*)(pi+i);
  float4 vo = *(const float4*)(po+i);
  float4 vf = *(const float4*)(pf+i);
  float4 vu = *(const float4*)(pu+i);
  float4 vc = *(const float4*)(c1+i);
  float4 h;
  float cx = sigf(vf.x)*vc.x + sigf(vi.x)*tanh_f(vu.x);
  float cy = sigf(vf.y)*vc.y + sigf(vi.y)*tanh_f(vu.y);
  float cz = sigf(vf.z)*vc.z + sigf(vi.z)*tanh_f(vu.z);
  float cw = sigf(vf.w)*vc.w + sigf(vi.w)*tanh_f(vu.w);
  h.x = sigf(vo.x)*tanh_f(cx); h.y = sigf(vo.y)*tanh_f(cy);
  h.z = sigf(vo.z)*tanh_f(cz); h.w = sigf(vo.w)*tanh_f(cw);
  *(float4*)(out+i) = h;
}

extern "C" void kernel_launch(void* const* d_in, const int* in_sizes, int n_in,
                              void* d_out, int out_size, void* d_ws, size_t ws_size,
                              hipStream_t stream){
  const int*   i_token  = (const int*)d_in[0];
  const int*   i_link   = (const int*)d_in[1];
  const int*   i_from   = (const int*)d_in[2];
  const int*   i_to     = (const int*)d_in[3];
  const float* emb_token= (const float*)d_in[4];
  const float* emb_link = (const float*)d_in[5];
  const float* Wc = (const float*)d_in[6];  const float* bc = (const float*)d_in[7];
  const float* Wl = (const float*)d_in[8];  const float* bl = (const float*)d_in[9];
  const float* Wi = (const float*)d_in[10]; const float* bi = (const float*)d_in[11];
  const float* Wo = (const float*)d_in[12]; const float* bo = (const float*)d_in[13];
  const float* Wf = (const float*)d_in[14]; const float* bf_ = (const float*)d_in[15];
  const float* Wu = (const float*)d_in[16]; const float* bu = (const float*)d_in[17];
  float* out = (float*)d_out;

  const size_t NB = (size_t)NNODES*128;
  float* ws  = (float*)d_ws;
  float* bufA = ws + 0*NB;  // node_emb -> pre_i
  float* bufB = ws + 1*NB;  // nodepart -> pre_o
  float* bufC = ws + 2*NB;  // x_in
  float* bufD = ws + 3*NB;  // x_out
  float* bufE = ws + 4*NB;  // h_in
  float* bufF = ws + 5*NB;  // h_out
  float* bufG = ws + 6*NB;  // c1
  float* bufH = ws + 7*NB;  // pre_u (L1) / pre_f (L2)
  float* linkpart = ws + 8*NB;                       // 50*128 floats
  int*   ia = (int*)(ws + 8*NB + 50*128);
  int* cnt_to   = ia + 0*NNODES;
  int* cnt_from = ia + 1*NNODES;   // cnt_to/cnt_from contiguous for one memset
  int* off_to   = ia + 2*NNODES;
  int* cur_to   = ia + 3*NNODES;
  int* off_from = ia + 4*NNODES;
  int* cur_from = ia + 5*NNODES;
  int* pay_to   = ia + 6*NNODES;
  int* pay_from = pay_to + NEDGES;

  const int GB = (NNODES + 63)/64;   // 782 gemm blocks
  const int GE = (NEDGES + 255)/256; // 3125 edge blocks
  const int GN = (NNODES + 7)/8;     // 6250 gather blocks

  // CSR build
  hipMemsetAsync(cnt_to, 0, 2*NNODES*sizeof(int), stream);
  k_hist<<<GE,256,0,stream>>>(i_to, i_from, cnt_to, cnt_from);
  k_scan<<<2,256,0,stream>>>(cnt_to, off_to, cur_to, cnt_from, off_from, cur_from);
  k_fill<<<GE,256,0,stream>>>(i_link, i_from, i_to, cur_to, cur_from, pay_to, pay_from);
  // after k_fill, cur_* hold segment END offsets

  k_linkpart<<<50,128,0,stream>>>(emb_link, Wl, bl, linkpart);
  k_node_emb<<<GB,256,0,stream>>>(i_token, emb_token, Wc, bc, bufA);
  // nodepart = node_emb @ Wl[64:192]
  k_gemm<<<GB,256,0,stream>>>(bufA,nullptr,nullptr,nullptr,1, Wl + 64*128, nullptr, bufB);

  // x_in / x_out via gather (no atomics, no memset)
  k_gather_xin <<<GN,256,0,stream>>>(off_to,  cur_to,  pay_to,  linkpart, bufB, bufC);
  k_gather_xout<<<GN,256,0,stream>>>(off_from,cur_from,pay_from,linkpart, bufB, bufD);

  // layer-1 gate preacts (h=0 -> only first 256 rows of W; fg unused since c=0)
  k_gemm<<<GB,256,0,stream>>>(bufC,bufD,nullptr,nullptr,2, Wi, bi, bufA);
  k_gemm<<<GB,256,0,stream>>>(bufC,bufD,nullptr,nullptr,2, Wo, bo, bufB);
  k_gemm<<<GB,256,0,stream>>>(bufC,bufD,nullptr,nullptr,2, Wu, bu, bufH);
  k_layer1<<<(int)(NB/4/256),256,0,stream>>>(bufA,bufB,bufH,bufG,out);

  // h_in / h_out via gather
  k_gather_sum<<<GN,256,0,stream>>>(off_to,  cur_to,  pay_to,  out, bufE);
  k_gather_sum<<<GN,256,0,stream>>>(off_from,cur_from,pay_from,out, bufF);

  // layer-2 gate preacts
  k_gemm<<<GB,256,0,stream>>>(bufC,bufD,bufE,bufF,4, Wi, bi, bufA);
  k_gemm<<<GB,256,0,stream>>>(bufC,bufD,bufE,bufF,4, Wo, bo, bufB);
  k_gemm<<<GB,256,0,stream>>>(bufC,bufD,bufE,bufF,4, Wf, bf_, bufH);
  k_gemm<<<GB,256,0,stream>>>(bufC,bufD,bufE,bufF,4, Wu, bu, out);
  k_layer2<<<(int)(NB/4/256),256,0,stream>>>(bufA,bufB,bufH,out,bufG,out);
}

// Round 3
// 836.430 us; speedup vs baseline: 7.3920x; 1.6285x over previous
//
#include <hip/hip_runtime.h>
#include <math.h>

#define NNODES 50000
#define NEDGES 800000

typedef __attribute__((ext_vector_type(8))) short s16x8;
typedef __attribute__((ext_vector_type(8))) unsigned short u16x8;
typedef __attribute__((ext_vector_type(4))) unsigned short u16x4;
typedef __attribute__((ext_vector_type(4))) float f32x4;

__device__ __forceinline__ float sigf(float x){ return 1.0f/(1.0f+__expf(-x)); }
__device__ __forceinline__ float tanh_f(float x){
  x = fminf(15.0f, fmaxf(-15.0f, x));
  float e = __expf(-2.0f*x);
  return (1.0f-e)/(1.0f+e);
}
__device__ __forceinline__ unsigned short f2b(float f){
  union{float f; unsigned u;} v; v.f = f;
  unsigned r = (v.u + 0x7FFFu + ((v.u>>16)&1u)) >> 16;
  return (unsigned short)r;
}
__device__ __forceinline__ float b2f(unsigned short b){
  union{unsigned u; float f;} v; v.u = ((unsigned)b)<<16; return v.f;
}

// linkpart[l][d] = bl[d] + sum_k emb_link[l][k]*Wl[k][d]
__global__ void k_linkpart(const float* __restrict__ emb_link, const float* __restrict__ Wl,
                           const float* __restrict__ bl, float* __restrict__ lp){
  int l = blockIdx.x, d = threadIdx.x;
  float acc = bl[d];
  #pragma unroll 8
  for(int k=0;k<64;k++) acc += emb_link[l*64+k]*Wl[k*128+d];
  lp[l*128+d] = acc;
}

// WgT[n][k] = bf16(W_{n/128}[k][n%128]), n<512, k<512
__global__ void k_prepw(const float* __restrict__ Wi, const float* __restrict__ Wo,
                        const float* __restrict__ Wf, const float* __restrict__ Wu,
                        unsigned short* __restrict__ WgT){
  int n = blockIdx.x; int k = threadIdx.x;
  const float* W = (n<128)? Wi : (n<256)? Wo : (n<384)? Wf : Wu;
  WgT[(size_t)n*512 + k] = f2b(W[(size_t)k*128 + (n&127)]);
}

// node_emb = tanh(gather(emb_token,i_token) @ Wc + bc); fp32 vector GEMM
__global__ __launch_bounds__(256) void k_node_emb(const int* __restrict__ i_token,
      const float* __restrict__ emb_token, const float* __restrict__ Wc,
      const float* __restrict__ bc, float* __restrict__ out){
  __shared__ float As[64][61];
  __shared__ float Wt[60][128];
  __shared__ int rowidx[64];
  int t = threadIdx.x;
  int m0 = blockIdx.x*64;
  if(t<64){ int m = m0+t; rowidx[t] = (m<NNODES)? i_token[m] : 0; }
  int cg = t & 15, rg = t >> 4;
  float acc[4][8];
  float4 b0 = *(const float4*)(bc + cg*8);
  float4 b1 = *(const float4*)(bc + cg*8+4);
  #pragma unroll
  for(int r=0;r<4;r++){
    acc[r][0]=b0.x; acc[r][1]=b0.y; acc[r][2]=b0.z; acc[r][3]=b0.w;
    acc[r][4]=b1.x; acc[r][5]=b1.y; acc[r][6]=b1.z; acc[r][7]=b1.w;
  }
  __syncthreads();
  for(int kt=0; kt<5; kt++){
    #pragma unroll
    for(int j=0;j<15;j++){
      int idx = t + j*256;
      int r = idx/60, k = idx - r*60;
      As[r][k] = emb_token[(size_t)rowidx[r]*300 + kt*60 + k];
    }
    #pragma unroll
    for(int j=0;j<30;j++){
      int idx = t + j*256;
      int k = idx >> 7, c = idx & 127;
      Wt[k][c] = Wc[(size_t)(kt*60+k)*128 + c];
    }
    __syncthreads();
    #pragma unroll 4
    for(int k=0;k<60;k++){
      float4 w0 = *(const float4*)&Wt[k][cg*8];
      float4 w1 = *(const float4*)&Wt[k][cg*8+4];
      #pragma unroll
      for(int r=0;r<4;r++){
        float a = As[rg*4+r][k];
        acc[r][0] += a*w0.x; acc[r][1] += a*w0.y; acc[r][2] += a*w0.z; acc[r][3] += a*w0.w;
        acc[r][4] += a*w1.x; acc[r][5] += a*w1.y; acc[r][6] += a*w1.z; acc[r][7] += a*w1.w;
      }
    }
    __syncthreads();
  }
  #pragma unroll
  for(int r=0;r<4;r++){
    int m = m0 + rg*4 + r;
    if(m < NNODES){
      float4 o0 = make_float4(tanh_f(acc[r][0]),tanh_f(acc[r][1]),tanh_f(acc[r][2]),tanh_f(acc[r][3]));
      float4 o1 = make_float4(tanh_f(acc[r][4]),tanh_f(acc[r][5]),tanh_f(acc[r][6]),tanh_f(acc[r][7]));
      *(float4*)(out + (size_t)m*128 + cg*8)     = o0;
      *(float4*)(out + (size_t)m*128 + cg*8 + 4) = o1;
    }
  }
}

// npart = node_emb @ Wl[64:192]  (fp32 vector GEMM, K=128, no bias)
__global__ __launch_bounds__(256) void k_gemm1(const float* __restrict__ A,
      const float* __restrict__ W, float* __restrict__ C){
  __shared__ float As[64][33];
  __shared__ float Wt[32][128];
  int t = threadIdx.x;
  int m0 = blockIdx.x*64;
  int cg = t & 15, rg = t >> 4;
  float acc[4][8];
  #pragma unroll
  for(int r=0;r<4;r++)
    #pragma unroll
    for(int j=0;j<8;j++) acc[r][j]=0.f;
  for(int kt=0;kt<4;kt++){
    #pragma unroll
    for(int j=0;j<2;j++){
      int f4 = t + j*256;
      int r = f4 >> 3, c4 = f4 & 7;
      int m = m0 + r; if(m >= NNODES) m = NNODES-1;
      float4 v = *(const float4*)(A + (size_t)m*128 + kt*32 + c4*4);
      As[r][c4*4+0]=v.x; As[r][c4*4+1]=v.y; As[r][c4*4+2]=v.z; As[r][c4*4+3]=v.w;
    }
    #pragma unroll
    for(int j=0;j<4;j++){
      int f4 = t + j*256;
      int k = f4 >> 5, c4 = f4 & 31;
      float4 v = *(const float4*)(W + (size_t)(kt*32 + k)*128 + c4*4);
      *(float4*)&Wt[k][c4*4] = v;
    }
    __syncthreads();
    #pragma unroll 4
    for(int k=0;k<32;k++){
      float4 w0 = *(const float4*)&Wt[k][cg*8];
      float4 w1 = *(const float4*)&Wt[k][cg*8+4];
      #pragma unroll
      for(int r=0;r<4;r++){
        float a = As[rg*4+r][k];
        acc[r][0] += a*w0.x; acc[r][1] += a*w0.y; acc[r][2] += a*w0.z; acc[r][3] += a*w0.w;
        acc[r][4] += a*w1.x; acc[r][5] += a*w1.y; acc[r][6] += a*w1.z; acc[r][7] += a*w1.w;
      }
    }
    __syncthreads();
  }
  #pragma unroll
  for(int r=0;r<4;r++){
    int m = m0 + rg*4 + r;
    if(m < NNODES){
      *(float4*)(C + (size_t)m*128 + cg*8)     = make_float4(acc[r][0],acc[r][1],acc[r][2],acc[r][3]);
      *(float4*)(C + (size_t)m*128 + cg*8 + 4) = make_float4(acc[r][4],acc[r][5],acc[r][6],acc[r][7]);
    }
  }
}

// ---------------- CSR build ----------------
__global__ void k_hist(const int* __restrict__ i_to, const int* __restrict__ i_from,
                       int* __restrict__ cnt_to, int* __restrict__ cnt_from){
  int e = blockIdx.x*256 + threadIdx.x;
  if(e >= NEDGES) return;
  atomicAdd(&cnt_to[i_to[e]], 1);
  atomicAdd(&cnt_from[i_from[e]], 1);
}

__global__ __launch_bounds__(256) void k_scan(const int* __restrict__ cnt_to, int* off_to, int* cur_to,
                                              const int* __restrict__ cnt_from, int* off_from, int* cur_from){
  const int* cnt = blockIdx.x ? cnt_from : cnt_to;
  int* off = blockIdx.x ? off_from : off_to;
  int* cur = blockIdx.x ? cur_from : cur_to;
  __shared__ int part[256];
  int t = threadIdx.x;
  const int CH = 196;
  int base = t*CH;
  int s = 0;
  for(int i=0;i<CH;i++){ int idx = base+i; if(idx<NNODES) s += cnt[idx]; }
  part[t] = s; __syncthreads();
  for(int d=1; d<256; d<<=1){
    int v = (t>=d) ? part[t-d] : 0;
    __syncthreads();
    part[t] += v;
    __syncthreads();
  }
  int run = (t==0) ? 0 : part[t-1];
  for(int i=0;i<CH;i++){
    int idx = base+i;
    if(idx<NNODES){ off[idx]=run; cur[idx]=run; run += cnt[idx]; }
  }
}

__global__ void k_fill(const int* __restrict__ i_link, const int* __restrict__ i_from,
                       const int* __restrict__ i_to,
                       int* __restrict__ cur_to, int* __restrict__ cur_from,
                       int* __restrict__ pay_to, int* __restrict__ pay_from){
  int e = blockIdx.x*256 + threadIdx.x;
  if(e >= NEDGES) return;
  int il = i_link[e], f = i_from[e], tt = i_to[e];
  int p1 = atomicAdd(&cur_to[tt], 1);  pay_to[p1]  = f  | (il<<16);
  int p2 = atomicAdd(&cur_from[f], 1); pay_from[p2] = tt | (il<<16);
}

// ---------------- gathers ----------------
// x_in[v] = sum tanh(lp[il] + npart[src]) -> bf16
__global__ __launch_bounds__(256) void k_gather_xin(const int* __restrict__ off, const int* __restrict__ end,
      const int* __restrict__ pay, const float* __restrict__ lp,
      const float* __restrict__ npart, unsigned short* __restrict__ out){
  int n = blockIdx.x*8 + (threadIdx.x>>5);
  if(n >= NNODES) return;
  int c = (threadIdx.x & 31)*4;
  float4 acc = make_float4(0.f,0.f,0.f,0.f);
  int s = off[n], e = end[n];
  for(int j=s;j<e;j++){
    int p = pay[j];
    int src = p & 0xFFFF, il = p >> 16;
    float4 a = *(const float4*)(lp + il*128 + c);
    float4 b = *(const float4*)(npart + (size_t)src*128 + c);
    acc.x += tanh_f(a.x+b.x); acc.y += tanh_f(a.y+b.y);
    acc.z += tanh_f(a.z+b.z); acc.w += tanh_f(a.w+b.w);
  }
  u16x4 o; o[0]=f2b(acc.x); o[1]=f2b(acc.y); o[2]=f2b(acc.z); o[3]=f2b(acc.w);
  *(u16x4*)(out + (size_t)n*128 + c) = o;
}

// x_out[u] = sum tanh(lp[il] + npart[u]) -> bf16
__global__ __launch_bounds__(256) void k_gather_xout(const int* __restrict__ off, const int* __restrict__ end,
      const int* __restrict__ pay, const float* __restrict__ lp,
      const float* __restrict__ npart, unsigned short* __restrict__ out){
  int n = blockIdx.x*8 + (threadIdx.x>>5);
  if(n >= NNODES) return;
  int c = (threadIdx.x & 31)*4;
  float4 b = *(const float4*)(npart + (size_t)n*128 + c);
  float4 acc = make_float4(0.f,0.f,0.f,0.f);
  int s = off[n], e = end[n];
  for(int j=s;j<e;j++){
    int p = pay[j];
    int il = p >> 16;
    float4 a = *(const float4*)(lp + il*128 + c);
    acc.x += tanh_f(a.x+b.x); acc.y += tanh_f(a.y+b.y);
    acc.z += tanh_f(a.z+b.z); acc.w += tanh_f(a.w+b.w);
  }
  u16x4 o; o[0]=f2b(acc.x); o[1]=f2b(acc.y); o[2]=f2b(acc.z); o[3]=f2b(acc.w);
  *(u16x4*)(out + (size_t)n*128 + c) = o;
}

// out[n] = sum src_bf16[pay[j] & 0xFFFF]  -> bf16
__global__ __launch_bounds__(256) void k_gather_sum(const int* __restrict__ off, const int* __restrict__ end,
      const int* __restrict__ pay, const unsigned short* __restrict__ src, unsigned short* __restrict__ out){
  int n = blockIdx.x*8 + (threadIdx.x>>5);
  if(n >= NNODES) return;
  int c = (threadIdx.x & 31)*4;
  float s0=0.f,s1=0.f,s2=0.f,s3=0.f;
  int s = off[n], e = end[n];
  for(int j=s;j<e;j++){
    int v = pay[j] & 0xFFFF;
    u16x4 a = *(const u16x4*)(src + (size_t)v*128 + c);
    s0 += b2f(a[0]); s1 += b2f(a[1]); s2 += b2f(a[2]); s3 += b2f(a[3]);
  }
  u16x4 o; o[0]=f2b(s0); o[1]=f2b(s1); o[2]=f2b(s2); o[3]=f2b(s3);
  *(u16x4*)(out + (size_t)n*128 + c) = o;
}

// ---------------- fused MFMA gate GEMM + LSTM cell ----------------
// P=2: layer1 (K=256, inp=[x_in,x_out]); writes c1 (fp32) + h1 (bf16)
// P=4: layer2 (K=512, inp=[x_in,x_out,h_in,h_out]); reads c1, writes h (fp32)
template<int P>
__global__ __launch_bounds__(256,2) void k_gates(
    const unsigned short* __restrict__ x0, const unsigned short* __restrict__ x1,
    const unsigned short* __restrict__ x2, const unsigned short* __restrict__ x3,
    const unsigned short* __restrict__ WgT,
    const float* __restrict__ bi, const float* __restrict__ bo,
    const float* __restrict__ bfg, const float* __restrict__ bu,
    float* __restrict__ cbuf, unsigned short* __restrict__ h1,
    float* __restrict__ hout)
{
  __shared__ unsigned short As[64*40];   // 64 rows x 32 k, pad to 40
  int t = threadIdx.x;
  int m0 = blockIdx.x*64;
  int w = t>>6; int l = t&63;
  int lm = l&15, kb = l>>4;
  f32x4 acc[2][4][4];  // [colgrp][gate][rowtile]
  #pragma unroll
  for(int a=0;a<2;a++)
    #pragma unroll
    for(int g=0;g<4;g++)
      #pragma unroll
      for(int r=0;r<4;r++) acc[a][g][r]=(f32x4){0.f,0.f,0.f,0.f};
  // A staging indices: thread -> (row, 16B chunk)
  int sr = t>>2, sp = t&3;
  int sm = m0 + sr; if(sm >= NNODES) sm = NNODES-1;
  size_t soff = (size_t)sm*128 + sp*8;
  const int KSTEPS = P*4;
  for(int ks=0; ks<KSTEPS; ks++){
    const unsigned short* src;
    if(P==2) src = (ks<4)? x0 : x1;
    else     src = (ks<4)? x0 : (ks<8)? x1 : (ks<12)? x2 : x3;
    int d0 = (ks&3)*32;
    u16x8 v = *(const u16x8*)(src + soff + d0);
    *(u16x8*)(As + sr*40 + sp*8) = v;
    __syncthreads();
    int k0 = ks*32;
    s16x8 af[4];
    #pragma unroll
    for(int rt=0; rt<4; rt++)
      af[rt] = *(const s16x8*)(As + (16*rt+lm)*40 + kb*8);
    #pragma unroll
    for(int c=0;c<2;c++){
      #pragma unroll
      for(int g=0;g<4;g++){
        int n = 16*(8*g + 2*w + c) + lm;
        s16x8 bfr = *(const s16x8*)(WgT + (size_t)n*512 + k0 + kb*8);
        #pragma unroll
        for(int rt=0; rt<4; rt++)
          acc[c][g][rt] = __builtin_amdgcn_mfma_f32_16x16x32_bf16(af[rt], bfr, acc[c][g][rt], 0,0,0);
      }
    }
    __syncthreads();
  }
  // epilogue: C/D layout col=lane&15, row=(lane>>4)*4+reg
  #pragma unroll
  for(int c=0;c<2;c++){
    int d = 16*(2*w+c) + lm;
    float vbi = bi[d], vbo = bo[d], vbu = bu[d];
    float vbf = (P==4)? bfg[d] : 0.f;
    #pragma unroll
    for(int rt=0; rt<4; rt++){
      #pragma unroll
      for(int reg=0; reg<4; reg++){
        int m = m0 + 16*rt + kb*4 + reg;
        if(m < NNODES){
          size_t o = (size_t)m*128 + d;
          float pi = acc[c][0][rt][reg] + vbi;
          float po = acc[c][1][rt][reg] + vbo;
          float pu = acc[c][3][rt][reg] + vbu;
          if(P==2){
            float c1v = sigf(pi)*tanh_f(pu);
            float hv  = sigf(po)*tanh_f(c1v);
            cbuf[o] = c1v;
            h1[o] = f2b(hv);
          } else {
            float pf = acc[c][2][rt][reg] + vbf;
            float c2 = sigf(pf)*cbuf[o] + sigf(pi)*tanh_f(pu);
            hout[o] = sigf(po)*tanh_f(c2);
          }
        }
      }
    }
  }
}

extern "C" void kernel_launch(void* const* d_in, const int* in_sizes, int n_in,
                              void* d_out, int out_size, void* d_ws, size_t ws_size,
                              hipStream_t stream){
  const int*   i_token  = (const int*)d_in[0];
  const int*   i_link   = (const int*)d_in[1];
  const int*   i_from   = (const int*)d_in[2];
  const int*   i_to     = (const int*)d_in[3];
  const float* emb_token= (const float*)d_in[4];
  const float* emb_link = (const float*)d_in[5];
  const float* Wc = (const float*)d_in[6];  const float* bc = (const float*)d_in[7];
  const float* Wl = (const float*)d_in[8];  const float* bl = (const float*)d_in[9];
  const float* Wi = (const float*)d_in[10]; const float* bi = (const float*)d_in[11];
  const float* Wo = (const float*)d_in[12]; const float* bo = (const float*)d_in[13];
  const float* Wf = (const float*)d_in[14]; const float* bf_ = (const float*)d_in[15];
  const float* Wu = (const float*)d_in[16]; const float* bu = (const float*)d_in[17];
  float* out = (float*)d_out;

  const size_t NB = (size_t)NNODES*128;
  float* bufA   = (float*)d_ws;            // node_emb
  float* npart  = bufA + NB;
  float* c1buf  = npart + NB;
  unsigned short* xin   = (unsigned short*)(c1buf + NB);
  unsigned short* xout  = xin + NB;
  unsigned short* hin   = xout + NB;
  unsigned short* houtb = hin + NB;
  unsigned short* h1    = houtb + NB;
  unsigned short* WgT   = h1 + NB;
  float* linkpart = (float*)(WgT + 512*512);
  int* ia = (int*)(linkpart + 50*128);
  int* cnt_to   = ia + 0*NNODES;
  int* cnt_from = ia + 1*NNODES;
  int* off_to   = ia + 2*NNODES;
  int* cur_to   = ia + 3*NNODES;
  int* off_from = ia + 4*NNODES;
  int* cur_from = ia + 5*NNODES;
  int* pay_to   = ia + 6*NNODES;
  int* pay_from = pay_to + NEDGES;

  const int GB = (NNODES + 63)/64;   // 782
  const int GE = (NEDGES + 255)/256; // 3125
  const int GN = (NNODES + 7)/8;     // 6250

  // CSR build
  hipMemsetAsync(cnt_to, 0, 2*NNODES*sizeof(int), stream);
  k_hist<<<GE,256,0,stream>>>(i_to, i_from, cnt_to, cnt_from);
  k_scan<<<2,256,0,stream>>>(cnt_to, off_to, cur_to, cnt_from, off_from, cur_from);
  k_fill<<<GE,256,0,stream>>>(i_link, i_from, i_to, cur_to, cur_from, pay_to, pay_from);

  // weights + node features
  k_prepw<<<512,512,0,stream>>>(Wi, Wo, Wf, Wu, WgT);
  k_linkpart<<<50,128,0,stream>>>(emb_link, Wl, bl, linkpart);
  k_node_emb<<<GB,256,0,stream>>>(i_token, emb_token, Wc, bc, bufA);
  k_gemm1<<<GB,256,0,stream>>>(bufA, Wl + 64*128, npart);

  // x gathers -> bf16
  k_gather_xin <<<GN,256,0,stream>>>(off_to,  cur_to,  pay_to,  linkpart, npart, xin);
  k_gather_xout<<<GN,256,0,stream>>>(off_from,cur_from,pay_from,linkpart, npart, xout);

  // layer 1 fused
  k_gates<2><<<GB,256,0,stream>>>(xin, xout, nullptr, nullptr, WgT,
                                  bi, bo, bf_, bu, c1buf, h1, nullptr);

  // h gathers -> bf16
  k_gather_sum<<<GN,256,0,stream>>>(off_to,  cur_to,  pay_to,  h1, hin);
  k_gather_sum<<<GN,256,0,stream>>>(off_from,cur_from,pay_from,h1, houtb);

  // layer 2 fused
  k_gates<4><<<GB,256,0,stream>>>(xin, xout, hin, houtb, WgT,
                                  bi, bo, bf_, bu, c1buf, nullptr, out);
}

// Round 4
// 616.163 us; speedup vs baseline: 10.0346x; 1.3575x over previous
//
#include <hip/hip_runtime.h>
#include <math.h>

#define NNODES 50000
#define NEDGES 800000
#define NBLK 196   // ceil(50000/256)

typedef __attribute__((ext_vector_type(8))) short s16x8;
typedef __attribute__((ext_vector_type(8))) unsigned short u16x8;
typedef __attribute__((ext_vector_type(4))) unsigned short u16x4;
typedef __attribute__((ext_vector_type(4))) float f32x4;

__device__ __forceinline__ float sigf(float x){ return 1.0f/(1.0f+__expf(-x)); }
__device__ __forceinline__ float tanh_f(float x){
  x = fminf(15.0f, fmaxf(-15.0f, x));
  float e = __expf(-2.0f*x);
  return (1.0f-e)/(1.0f+e);
}
__device__ __forceinline__ unsigned short f2b(float f){
  union{float f; unsigned u;} v; v.f = f;
  unsigned r = (v.u + 0x7FFFu + ((v.u>>16)&1u)) >> 16;
  return (unsigned short)r;
}
__device__ __forceinline__ float b2f(unsigned short b){
  union{unsigned u; float f;} v; v.u = ((unsigned)b)<<16; return v.f;
}

// linkpart[l][d] = bf16(bl[d] + sum_k emb_link[l][k]*Wl[k][d])
__global__ void k_linkpart(const float* __restrict__ emb_link, const float* __restrict__ Wl,
                           const float* __restrict__ bl, unsigned short* __restrict__ lp){
  int l = blockIdx.x, d = threadIdx.x;
  float acc = bl[d];
  #pragma unroll 8
  for(int k=0;k<64;k++) acc += emb_link[l*64+k]*Wl[k*128+d];
  lp[l*128+d] = f2b(acc);
}

// WgT[n][k] = bf16(W_{n/128}[k][n%128]), n<512, k<512
__global__ void k_prepw(const float* __restrict__ Wi, const float* __restrict__ Wo,
                        const float* __restrict__ Wf, const float* __restrict__ Wu,
                        unsigned short* __restrict__ WgT){
  int n = blockIdx.x; int k = threadIdx.x;
  const float* W = (n<128)? Wi : (n<256)? Wo : (n<384)? Wf : Wu;
  WgT[(size_t)n*512 + k] = f2b(W[(size_t)k*128 + (n&127)]);
}

// node_emb = tanh(gather(emb_token,i_token) @ Wc + bc); fp32 vector GEMM
__global__ __launch_bounds__(256) void k_node_emb(const int* __restrict__ i_token,
      const float* __restrict__ emb_token, const float* __restrict__ Wc,
      const float* __restrict__ bc, float* __restrict__ out){
  __shared__ float As[64][61];
  __shared__ float Wt[60][128];
  __shared__ int rowidx[64];
  int t = threadIdx.x;
  int m0 = blockIdx.x*64;
  if(t<64){ int m = m0+t; rowidx[t] = (m<NNODES)? i_token[m] : 0; }
  int cg = t & 15, rg = t >> 4;
  float acc[4][8];
  float4 b0 = *(const float4*)(bc + cg*8);
  float4 b1 = *(const float4*)(bc + cg*8+4);
  #pragma unroll
  for(int r=0;r<4;r++){
    acc[r][0]=b0.x; acc[r][1]=b0.y; acc[r][2]=b0.z; acc[r][3]=b0.w;
    acc[r][4]=b1.x; acc[r][5]=b1.y; acc[r][6]=b1.z; acc[r][7]=b1.w;
  }
  __syncthreads();
  for(int kt=0; kt<5; kt++){
    #pragma unroll
    for(int j=0;j<15;j++){
      int idx = t + j*256;
      int r = idx/60, k = idx - r*60;
      As[r][k] = emb_token[(size_t)rowidx[r]*300 + kt*60 + k];
    }
    #pragma unroll
    for(int j=0;j<30;j++){
      int idx = t + j*256;
      int k = idx >> 7, c = idx & 127;
      Wt[k][c] = Wc[(size_t)(kt*60+k)*128 + c];
    }
    __syncthreads();
    #pragma unroll 4
    for(int k=0;k<60;k++){
      float4 w0 = *(const float4*)&Wt[k][cg*8];
      float4 w1 = *(const float4*)&Wt[k][cg*8+4];
      #pragma unroll
      for(int r=0;r<4;r++){
        float a = As[rg*4+r][k];
        acc[r][0] += a*w0.x; acc[r][1] += a*w0.y; acc[r][2] += a*w0.z; acc[r][3] += a*w0.w;
        acc[r][4] += a*w1.x; acc[r][5] += a*w1.y; acc[r][6] += a*w1.z; acc[r][7] += a*w1.w;
      }
    }
    __syncthreads();
  }
  #pragma unroll
  for(int r=0;r<4;r++){
    int m = m0 + rg*4 + r;
    if(m < NNODES){
      float4 o0 = make_float4(tanh_f(acc[r][0]),tanh_f(acc[r][1]),tanh_f(acc[r][2]),tanh_f(acc[r][3]));
      float4 o1 = make_float4(tanh_f(acc[r][4]),tanh_f(acc[r][5]),tanh_f(acc[r][6]),tanh_f(acc[r][7]));
      *(float4*)(out + (size_t)m*128 + cg*8)     = o0;
      *(float4*)(out + (size_t)m*128 + cg*8 + 4) = o1;
    }
  }
}

// npart = bf16(node_emb @ Wl[64:192])  (fp32 vector GEMM, K=128, no bias)
__global__ __launch_bounds__(256) void k_gemm1(const float* __restrict__ A,
      const float* __restrict__ W, unsigned short* __restrict__ C){
  __shared__ float As[64][33];
  __shared__ float Wt[32][128];
  int t = threadIdx.x;
  int m0 = blockIdx.x*64;
  int cg = t & 15, rg = t >> 4;
  float acc[4][8];
  #pragma unroll
  for(int r=0;r<4;r++)
    #pragma unroll
    for(int j=0;j<8;j++) acc[r][j]=0.f;
  for(int kt=0;kt<4;kt++){
    #pragma unroll
    for(int j=0;j<2;j++){
      int f4 = t + j*256;
      int r = f4 >> 3, c4 = f4 & 7;
      int m = m0 + r; if(m >= NNODES) m = NNODES-1;
      float4 v = *(const float4*)(A + (size_t)m*128 + kt*32 + c4*4);
      As[r][c4*4+0]=v.x; As[r][c4*4+1]=v.y; As[r][c4*4+2]=v.z; As[r][c4*4+3]=v.w;
    }
    #pragma unroll
    for(int j=0;j<4;j++){
      int f4 = t + j*256;
      int k = f4 >> 5, c4 = f4 & 31;
      float4 v = *(const float4*)(W + (size_t)(kt*32 + k)*128 + c4*4);
      *(float4*)&Wt[k][c4*4] = v;
    }
    __syncthreads();
    #pragma unroll 4
    for(int k=0;k<32;k++){
      float4 w0 = *(const float4*)&Wt[k][cg*8];
      float4 w1 = *(const float4*)&Wt[k][cg*8+4];
      #pragma unroll
      for(int r=0;r<4;r++){
        float a = As[rg*4+r][k];
        acc[r][0] += a*w0.x; acc[r][1] += a*w0.y; acc[r][2] += a*w0.z; acc[r][3] += a*w0.w;
        acc[r][4] += a*w1.x; acc[r][5] += a*w1.y; acc[r][6] += a*w1.z; acc[r][7] += a*w1.w;
      }
    }
    __syncthreads();
  }
  #pragma unroll
  for(int r=0;r<4;r++){
    int m = m0 + rg*4 + r;
    if(m < NNODES){
      u16x8 o;
      #pragma unroll
      for(int j=0;j<8;j++) o[j] = f2b(acc[r][j]);
      *(u16x8*)(C + (size_t)m*128 + cg*8) = o;
    }
  }
}

// ---------------- CSR build ----------------
// one atomic pass: rank = old count
__global__ void k_hist(const int* __restrict__ i_to, const int* __restrict__ i_from,
                       int* __restrict__ cnt_to, int* __restrict__ cnt_from,
                       int* __restrict__ rank_to, int* __restrict__ rank_from){
  int e = blockIdx.x*256 + threadIdx.x;
  if(e >= NEDGES) return;
  rank_to[e]   = atomicAdd(&cnt_to[i_to[e]], 1);
  rank_from[e] = atomicAdd(&cnt_from[i_from[e]], 1);
}

// phase A: per-block sums (grid = 2*NBLK, dir = blockIdx.x >= NBLK)
__global__ __launch_bounds__(256) void k_scanA(const int* __restrict__ cnt_to,
      const int* __restrict__ cnt_from, int* __restrict__ bsum){
  int b = blockIdx.x; int dir = (b >= NBLK); int bb = dir? b-NBLK : b;
  const int* cnt = dir? cnt_from : cnt_to;
  int t = threadIdx.x;
  int idx = bb*256 + t;
  int c = (idx < NNODES)? cnt[idx] : 0;
  __shared__ int red[256];
  red[t] = c; __syncthreads();
  for(int s=128;s>0;s>>=1){ if(t<s) red[t]+=red[t+s]; __syncthreads(); }
  if(t==0) bsum[b] = red[0];
}

// phase B: exclusive scan of 2*NBLK block sums (1 block)
__global__ __launch_bounds__(256) void k_scanB(const int* __restrict__ bsum, int* __restrict__ bpre){
  __shared__ int sh[256];
  int t = threadIdx.x;
  for(int dir=0; dir<2; dir++){
    sh[t] = (t < NBLK)? bsum[dir*NBLK + t] : 0;
    __syncthreads();
    for(int d=1; d<256; d<<=1){
      int v = (t>=d)? sh[t-d] : 0;
      __syncthreads();
      sh[t] += v;
      __syncthreads();
    }
    if(t < NBLK) bpre[dir*NBLK + t] = (t==0)? 0 : sh[t-1];
    __syncthreads();
  }
}

// phase C: intra-block exclusive scan + block prefix -> off, end
__global__ __launch_bounds__(256) void k_scanC(const int* __restrict__ cnt_to,
      const int* __restrict__ cnt_from, const int* __restrict__ bpre,
      int* __restrict__ off_to, int* __restrict__ end_to,
      int* __restrict__ off_from, int* __restrict__ end_from){
  int b = blockIdx.x; int dir = (b >= NBLK); int bb = dir? b-NBLK : b;
  const int* cnt = dir? cnt_from : cnt_to;
  int* off = dir? off_from : off_to;
  int* end = dir? end_from : end_to;
  int t = threadIdx.x;
  int idx = bb*256 + t;
  int c = (idx < NNODES)? cnt[idx] : 0;
  __shared__ int sh[256];
  sh[t] = c; __syncthreads();
  for(int d=1; d<256; d<<=1){
    int v = (t>=d)? sh[t-d] : 0;
    __syncthreads();
    sh[t] += v;
    __syncthreads();
  }
  if(idx < NNODES){
    int o = bpre[b] + ((t==0)? 0 : sh[t-1]);
    off[idx] = o;
    end[idx] = o + c;
  }
}

// non-atomic placement using precomputed ranks
__global__ void k_place(const int* __restrict__ i_link, const int* __restrict__ i_from,
                        const int* __restrict__ i_to,
                        const int* __restrict__ off_to, const int* __restrict__ off_from,
                        const int* __restrict__ rank_to, const int* __restrict__ rank_from,
                        int* __restrict__ pay_to, int* __restrict__ pay_from){
  int e = blockIdx.x*256 + threadIdx.x;
  if(e >= NEDGES) return;
  int il = i_link[e], f = i_from[e], tt = i_to[e];
  pay_to[off_to[tt] + rank_to[e]]   = f  | (il<<16);
  pay_from[off_from[f] + rank_from[e]] = tt | (il<<16);
}

// ---------------- gathers ----------------
// x_in[v] = sum tanh(lp[il] + npart[src]) -> bf16   (lp, npart bf16)
__global__ __launch_bounds__(256) void k_gather_xin(const int* __restrict__ off, const int* __restrict__ end,
      const int* __restrict__ pay, const unsigned short* __restrict__ lp,
      const unsigned short* __restrict__ npart, unsigned short* __restrict__ out){
  int n = blockIdx.x*8 + (threadIdx.x>>5);
  if(n >= NNODES) return;
  int c = (threadIdx.x & 31)*4;
  float4 acc = make_float4(0.f,0.f,0.f,0.f);
  int s = off[n], e = end[n];
  for(int j=s;j<e;j++){
    int p = pay[j];
    int src = p & 0xFFFF, il = p >> 16;
    u16x4 a = *(const u16x4*)(lp + il*128 + c);
    u16x4 b = *(const u16x4*)(npart + (size_t)src*128 + c);
    acc.x += tanh_f(b2f(a[0])+b2f(b[0])); acc.y += tanh_f(b2f(a[1])+b2f(b[1]));
    acc.z += tanh_f(b2f(a[2])+b2f(b[2])); acc.w += tanh_f(b2f(a[3])+b2f(b[3]));
  }
  u16x4 o; o[0]=f2b(acc.x); o[1]=f2b(acc.y); o[2]=f2b(acc.z); o[3]=f2b(acc.w);
  *(u16x4*)(out + (size_t)n*128 + c) = o;
}

// x_out[u] = sum tanh(lp[il] + npart[u]) -> bf16
__global__ __launch_bounds__(256) void k_gather_xout(const int* __restrict__ off, const int* __restrict__ end,
      const int* __restrict__ pay, const unsigned short* __restrict__ lp,
      const unsigned short* __restrict__ npart, unsigned short* __restrict__ out){
  int n = blockIdx.x*8 + (threadIdx.x>>5);
  if(n >= NNODES) return;
  int c = (threadIdx.x & 31)*4;
  u16x4 bb = *(const u16x4*)(npart + (size_t)n*128 + c);
  float b0=b2f(bb[0]), b1=b2f(bb[1]), b2=b2f(bb[2]), b3=b2f(bb[3]);
  float4 acc = make_float4(0.f,0.f,0.f,0.f);
  int s = off[n], e = end[n];
  for(int j=s;j<e;j++){
    int p = pay[j];
    int il = p >> 16;
    u16x4 a = *(const u16x4*)(lp + il*128 + c);
    acc.x += tanh_f(b2f(a[0])+b0); acc.y += tanh_f(b2f(a[1])+b1);
    acc.z += tanh_f(b2f(a[2])+b2); acc.w += tanh_f(b2f(a[3])+b3);
  }
  u16x4 o; o[0]=f2b(acc.x); o[1]=f2b(acc.y); o[2]=f2b(acc.z); o[3]=f2b(acc.w);
  *(u16x4*)(out + (size_t)n*128 + c) = o;
}

// out[n] = sum src_bf16[pay[j] & 0xFFFF]  -> bf16
__global__ __launch_bounds__(256) void k_gather_sum(const int* __restrict__ off, const int* __restrict__ end,
      const int* __restrict__ pay, const unsigned short* __restrict__ src, unsigned short* __restrict__ out){
  int n = blockIdx.x*8 + (threadIdx.x>>5);
  if(n >= NNODES) return;
  int c = (threadIdx.x & 31)*4;
  float s0=0.f,s1=0.f,s2=0.f,s3=0.f;
  int s = off[n], e = end[n];
  for(int j=s;j<e;j++){
    int v = pay[j] & 0xFFFF;
    u16x4 a = *(const u16x4*)(src + (size_t)v*128 + c);
    s0 += b2f(a[0]); s1 += b2f(a[1]); s2 += b2f(a[2]); s3 += b2f(a[3]);
  }
  u16x4 o; o[0]=f2b(s0); o[1]=f2b(s1); o[2]=f2b(s2); o[3]=f2b(s3);
  *(u16x4*)(out + (size_t)n*128 + c) = o;
}

// ---------------- fused MFMA gate GEMM + LSTM cell ----------------
template<int P>
__global__ __launch_bounds__(256,2) void k_gates(
    const unsigned short* __restrict__ x0, const unsigned short* __restrict__ x1,
    const unsigned short* __restrict__ x2, const unsigned short* __restrict__ x3,
    const unsigned short* __restrict__ WgT,
    const float* __restrict__ bi, const float* __restrict__ bo,
    const float* __restrict__ bfg, const float* __restrict__ bu,
    float* __restrict__ cbuf, unsigned short* __restrict__ h1,
    float* __restrict__ hout)
{
  __shared__ unsigned short As[64*40];
  int t = threadIdx.x;
  int m0 = blockIdx.x*64;
  int w = t>>6; int l = t&63;
  int lm = l&15, kb = l>>4;
  f32x4 acc[2][4][4];
  #pragma unroll
  for(int a=0;a<2;a++)
    #pragma unroll
    for(int g=0;g<4;g++)
      #pragma unroll
      for(int r=0;r<4;r++) acc[a][g][r]=(f32x4){0.f,0.f,0.f,0.f};
  int sr = t>>2, sp = t&3;
  int sm = m0 + sr; if(sm >= NNODES) sm = NNODES-1;
  size_t soff = (size_t)sm*128 + sp*8;
  const int KSTEPS = P*4;
  for(int ks=0; ks<KSTEPS; ks++){
    const unsigned short* src;
    if(P==2) src = (ks<4)? x0 : x1;
    else     src = (ks<4)? x0 : (ks<8)? x1 : (ks<12)? x2 : x3;
    int d0 = (ks&3)*32;
    u16x8 v = *(const u16x8*)(src + soff + d0);
    *(u16x8*)(As + sr*40 + sp*8) = v;
    __syncthreads();
    int k0 = ks*32;
    s16x8 af[4];
    #pragma unroll
    for(int rt=0; rt<4; rt++)
      af[rt] = *(const s16x8*)(As + (16*rt+lm)*40 + kb*8);
    #pragma unroll
    for(int c=0;c<2;c++){
      #pragma unroll
      for(int g=0;g<4;g++){
        int n = 16*(8*g + 2*w + c) + lm;
        s16x8 bfr = *(const s16x8*)(WgT + (size_t)n*512 + k0 + kb*8);
        #pragma unroll
        for(int rt=0; rt<4; rt++)
          acc[c][g][rt] = __builtin_amdgcn_mfma_f32_16x16x32_bf16(af[rt], bfr, acc[c][g][rt], 0,0,0);
      }
    }
    __syncthreads();
  }
  #pragma unroll
  for(int c=0;c<2;c++){
    int d = 16*(2*w+c) + lm;
    float vbi = bi[d], vbo = bo[d], vbu = bu[d];
    float vbf = (P==4)? bfg[d] : 0.f;
    #pragma unroll
    for(int rt=0; rt<4; rt++){
      #pragma unroll
      for(int reg=0; reg<4; reg++){
        int m = m0 + 16*rt + kb*4 + reg;
        if(m < NNODES){
          size_t o = (size_t)m*128 + d;
          float pi = acc[c][0][rt][reg] + vbi;
          float po = acc[c][1][rt][reg] + vbo;
          float pu = acc[c][3][rt][reg] + vbu;
          if(P==2){
            float c1v = sigf(pi)*tanh_f(pu);
            float hv  = sigf(po)*tanh_f(c1v);
            cbuf[o] = c1v;
            h1[o] = f2b(hv);
          } else {
            float pf = acc[c][2][rt][reg] + vbf;
            float c2 = sigf(pf)*cbuf[o] + sigf(pi)*tanh_f(pu);
            hout[o] = sigf(po)*tanh_f(c2);
          }
        }
      }
    }
  }
}

extern "C" void kernel_launch(void* const* d_in, const int* in_sizes, int n_in,
                              void* d_out, int out_size, void* d_ws, size_t ws_size,
                              hipStream_t stream){
  const int*   i_token  = (const int*)d_in[0];
  const int*   i_link   = (const int*)d_in[1];
  const int*   i_from   = (const int*)d_in[2];
  const int*   i_to     = (const int*)d_in[3];
  const float* emb_token= (const float*)d_in[4];
  const float* emb_link = (const float*)d_in[5];
  const float* Wc = (const float*)d_in[6];  const float* bc = (const float*)d_in[7];
  const float* Wl = (const float*)d_in[8];  const float* bl = (const float*)d_in[9];
  const float* Wi = (const float*)d_in[10]; const float* bi = (const float*)d_in[11];
  const float* Wo = (const float*)d_in[12]; const float* bo = (const float*)d_in[13];
  const float* Wf = (const float*)d_in[14]; const float* bf_ = (const float*)d_in[15];
  const float* Wu = (const float*)d_in[16]; const float* bu = (const float*)d_in[17];
  float* out = (float*)d_out;

  const size_t NB = (size_t)NNODES*128;
  float* bufA   = (float*)d_ws;            // node_emb (fp32)
  float* c1buf  = bufA + NB;
  unsigned short* npart = (unsigned short*)(c1buf + NB);
  unsigned short* xin   = npart + NB;
  unsigned short* xout  = xin + NB;
  unsigned short* hin   = xout + NB;
  unsigned short* houtb = hin + NB;
  unsigned short* h1    = houtb + NB;
  unsigned short* WgT   = h1 + NB;
  unsigned short* linkpart = WgT + 512*512;
  int* ia = (int*)(linkpart + 50*128);
  int* cnt_to   = ia + 0*NNODES;
  int* cnt_from = ia + 1*NNODES;
  int* off_to   = ia + 2*NNODES;
  int* end_to   = ia + 3*NNODES;
  int* off_from = ia + 4*NNODES;
  int* end_from = ia + 5*NNODES;
  int* bsum     = ia + 6*NNODES;
  int* bpre     = bsum + 2*NBLK;
  int* pay_to   = bpre + 2*NBLK;
  int* pay_from = pay_to + NEDGES;
  int* rank_to  = pay_from + NEDGES;
  int* rank_from= rank_to + NEDGES;

  const int GB = (NNODES + 63)/64;   // 782
  const int GE = (NEDGES + 255)/256; // 3125
  const int GN = (NNODES + 7)/8;     // 6250

  // CSR build: 1 atomic pass + parallel scan + non-atomic place
  hipMemsetAsync(cnt_to, 0, 2*NNODES*sizeof(int), stream);
  k_hist<<<GE,256,0,stream>>>(i_to, i_from, cnt_to, cnt_from, rank_to, rank_from);
  k_scanA<<<2*NBLK,256,0,stream>>>(cnt_to, cnt_from, bsum);
  k_scanB<<<1,256,0,stream>>>(bsum, bpre);
  k_scanC<<<2*NBLK,256,0,stream>>>(cnt_to, cnt_from, bpre, off_to, end_to, off_from, end_from);
  k_place<<<GE,256,0,stream>>>(i_link, i_from, i_to, off_to, off_from,
                               rank_to, rank_from, pay_to, pay_from);

  // weights + node features
  k_prepw<<<512,512,0,stream>>>(Wi, Wo, Wf, Wu, WgT);
  k_linkpart<<<50,128,0,stream>>>(emb_link, Wl, bl, linkpart);
  k_node_emb<<<GB,256,0,stream>>>(i_token, emb_token, Wc, bc, bufA);
  k_gemm1<<<GB,256,0,stream>>>(bufA, Wl + 64*128, npart);

  // x gathers -> bf16
  k_gather_xin <<<GN,256,0,stream>>>(off_to,  end_to,  pay_to,  linkpart, npart, xin);
  k_gather_xout<<<GN,256,0,stream>>>(off_from,end_from,pay_from,linkpart, npart, xout);

  // layer 1 fused
  k_gates<2><<<GB,256,0,stream>>>(xin, xout, nullptr, nullptr, WgT,
                                  bi, bo, bf_, bu, c1buf, h1, nullptr);

  // h gathers -> bf16
  k_gather_sum<<<GN,256,0,stream>>>(off_to,  end_to,  pay_to,  h1, hin);
  k_gather_sum<<<GN,256,0,stream>>>(off_from,end_from,pay_from,h1, houtb);

  // layer 2 fused
  k_gates<4><<<GB,256,0,stream>>>(xin, xout, hin, houtb, WgT,
                                  bi, bo, bf_, bu, c1buf, nullptr, out);
}

// Round 5
// 601.400 us; speedup vs baseline: 10.2809x; 1.0245x over previous
//
#include <hip/hip_runtime.h>
#include <math.h>

#define NNODES 50000
#define NEDGES 800000
#define NBLK 196   // ceil(50000/256)

typedef __attribute__((ext_vector_type(8))) short s16x8;
typedef __attribute__((ext_vector_type(8))) unsigned short u16x8;
typedef __attribute__((ext_vector_type(4))) unsigned short u16x4;
typedef __attribute__((ext_vector_type(4))) float f32x4;

__device__ __forceinline__ float sigf(float x){ return 1.0f/(1.0f+__expf(-x)); }
__device__ __forceinline__ float tanh_f(float x){
  x = fminf(15.0f, fmaxf(-15.0f, x));
  float e = __expf(-2.0f*x);
  return (1.0f-e)/(1.0f+e);
}
__device__ __forceinline__ unsigned short f2b(float f){
  union{float f; unsigned u;} v; v.f = f;
  unsigned r = (v.u + 0x7FFFu + ((v.u>>16)&1u)) >> 16;
  return (unsigned short)r;
}
__device__ __forceinline__ float b2f(unsigned short b){
  union{unsigned u; float f;} v; v.u = ((unsigned)b)<<16; return v.f;
}

// linkpart[l][d] = bf16(bl[d] + sum_k emb_link[l][k]*Wl[k][d])
__global__ void k_linkpart(const float* __restrict__ emb_link, const float* __restrict__ Wl,
                           const float* __restrict__ bl, unsigned short* __restrict__ lp){
  int l = blockIdx.x, d = threadIdx.x;
  float acc = bl[d];
  #pragma unroll 8
  for(int k=0;k<64;k++) acc += emb_link[l*64+k]*Wl[k*128+d];
  lp[l*128+d] = f2b(acc);
}

// Fragment-major gate weights:
// Wfrag[((ks*32 + nt)*64 + l)*8 + j] = bf16(W_{n/128}[k][n%128])
//   n = nt*16 + (l&15), k = ks*32 + (l>>4)*8 + j
__global__ void k_prepw(const float* __restrict__ Wi, const float* __restrict__ Wo,
                        const float* __restrict__ Wf, const float* __restrict__ Wu,
                        unsigned short* __restrict__ Wfrag){
  int n = blockIdx.x; int k = threadIdx.x;
  const float* W = (n<128)? Wi : (n<256)? Wo : (n<384)? Wf : Wu;
  float v = W[(size_t)k*128 + (n&127)];
  int ks = k>>5, kb = (k>>3)&3, j = k&7;
  int nt = n>>4, lm = n&15;
  int l = lm + 16*kb;
  Wfrag[(size_t)(((ks*32 + nt)*64) + l)*8 + j] = f2b(v);
}

// node_emb = tanh(gather(emb_token,i_token) @ Wc + bc); fp32 vector GEMM
__global__ __launch_bounds__(256) void k_node_emb(const int* __restrict__ i_token,
      const float* __restrict__ emb_token, const float* __restrict__ Wc,
      const float* __restrict__ bc, float* __restrict__ out){
  __shared__ float As[64][61];
  __shared__ float Wt[60][128];
  __shared__ int rowidx[64];
  int t = threadIdx.x;
  int m0 = blockIdx.x*64;
  if(t<64){ int m = m0+t; rowidx[t] = (m<NNODES)? i_token[m] : 0; }
  int cg = t & 15, rg = t >> 4;
  float acc[4][8];
  float4 b0 = *(const float4*)(bc + cg*8);
  float4 b1 = *(const float4*)(bc + cg*8+4);
  #pragma unroll
  for(int r=0;r<4;r++){
    acc[r][0]=b0.x; acc[r][1]=b0.y; acc[r][2]=b0.z; acc[r][3]=b0.w;
    acc[r][4]=b1.x; acc[r][5]=b1.y; acc[r][6]=b1.z; acc[r][7]=b1.w;
  }
  __syncthreads();
  for(int kt=0; kt<5; kt++){
    #pragma unroll
    for(int j=0;j<15;j++){
      int idx = t + j*256;
      int r = idx/60, k = idx - r*60;
      As[r][k] = emb_token[(size_t)rowidx[r]*300 + kt*60 + k];
    }
    #pragma unroll
    for(int j=0;j<30;j++){
      int idx = t + j*256;
      int k = idx >> 7, c = idx & 127;
      Wt[k][c] = Wc[(size_t)(kt*60+k)*128 + c];
    }
    __syncthreads();
    #pragma unroll 4
    for(int k=0;k<60;k++){
      float4 w0 = *(const float4*)&Wt[k][cg*8];
      float4 w1 = *(const float4*)&Wt[k][cg*8+4];
      #pragma unroll
      for(int r=0;r<4;r++){
        float a = As[rg*4+r][k];
        acc[r][0] += a*w0.x; acc[r][1] += a*w0.y; acc[r][2] += a*w0.z; acc[r][3] += a*w0.w;
        acc[r][4] += a*w1.x; acc[r][5] += a*w1.y; acc[r][6] += a*w1.z; acc[r][7] += a*w1.w;
      }
    }
    __syncthreads();
  }
  #pragma unroll
  for(int r=0;r<4;r++){
    int m = m0 + rg*4 + r;
    if(m < NNODES){
      float4 o0 = make_float4(tanh_f(acc[r][0]),tanh_f(acc[r][1]),tanh_f(acc[r][2]),tanh_f(acc[r][3]));
      float4 o1 = make_float4(tanh_f(acc[r][4]),tanh_f(acc[r][5]),tanh_f(acc[r][6]),tanh_f(acc[r][7]));
      *(float4*)(out + (size_t)m*128 + cg*8)     = o0;
      *(float4*)(out + (size_t)m*128 + cg*8 + 4) = o1;
    }
  }
}

// npart = bf16(node_emb @ Wl[64:192])  (fp32 vector GEMM, K=128, no bias)
__global__ __launch_bounds__(256) void k_gemm1(const float* __restrict__ A,
      const float* __restrict__ W, unsigned short* __restrict__ C){
  __shared__ float As[64][33];
  __shared__ float Wt[32][128];
  int t = threadIdx.x;
  int m0 = blockIdx.x*64;
  int cg = t & 15, rg = t >> 4;
  float acc[4][8];
  #pragma unroll
  for(int r=0;r<4;r++)
    #pragma unroll
    for(int j=0;j<8;j++) acc[r][j]=0.f;
  for(int kt=0;kt<4;kt++){
    #pragma unroll
    for(int j=0;j<2;j++){
      int f4 = t + j*256;
      int r = f4 >> 3, c4 = f4 & 7;
      int m = m0 + r; if(m >= NNODES) m = NNODES-1;
      float4 v = *(const float4*)(A + (size_t)m*128 + kt*32 + c4*4);
      As[r][c4*4+0]=v.x; As[r][c4*4+1]=v.y; As[r][c4*4+2]=v.z; As[r][c4*4+3]=v.w;
    }
    #pragma unroll
    for(int j=0;j<4;j++){
      int f4 = t + j*256;
      int k = f4 >> 5, c4 = f4 & 31;
      float4 v = *(const float4*)(W + (size_t)(kt*32 + k)*128 + c4*4);
      *(float4*)&Wt[k][c4*4] = v;
    }
    __syncthreads();
    #pragma unroll 4
    for(int k=0;k<32;k++){
      float4 w0 = *(const float4*)&Wt[k][cg*8];
      float4 w1 = *(const float4*)&Wt[k][cg*8+4];
      #pragma unroll
      for(int r=0;r<4;r++){
        float a = As[rg*4+r][k];
        acc[r][0] += a*w0.x; acc[r][1] += a*w0.y; acc[r][2] += a*w0.z; acc[r][3] += a*w0.w;
        acc[r][4] += a*w1.x; acc[r][5] += a*w1.y; acc[r][6] += a*w1.z; acc[r][7] += a*w1.w;
      }
    }
    __syncthreads();
  }
  #pragma unroll
  for(int r=0;r<4;r++){
    int m = m0 + rg*4 + r;
    if(m < NNODES){
      u16x8 o;
      #pragma unroll
      for(int j=0;j<8;j++) o[j] = f2b(acc[r][j]);
      *(u16x8*)(C + (size_t)m*128 + cg*8) = o;
    }
  }
}

// ---------------- CSR build ----------------
__global__ void k_hist(const int* __restrict__ i_to, const int* __restrict__ i_from,
                       int* __restrict__ cnt_to, int* __restrict__ cnt_from,
                       int* __restrict__ rank_to, int* __restrict__ rank_from){
  int e = blockIdx.x*256 + threadIdx.x;
  if(e >= NEDGES) return;
  rank_to[e]   = atomicAdd(&cnt_to[i_to[e]], 1);
  rank_from[e] = atomicAdd(&cnt_from[i_from[e]], 1);
}

__global__ __launch_bounds__(256) void k_scanA(const int* __restrict__ cnt_to,
      const int* __restrict__ cnt_from, int* __restrict__ bsum){
  int b = blockIdx.x; int dir = (b >= NBLK); int bb = dir? b-NBLK : b;
  const int* cnt = dir? cnt_from : cnt_to;
  int t = threadIdx.x;
  int idx = bb*256 + t;
  int c = (idx < NNODES)? cnt[idx] : 0;
  __shared__ int red[256];
  red[t] = c; __syncthreads();
  for(int s=128;s>0;s>>=1){ if(t<s) red[t]+=red[t+s]; __syncthreads(); }
  if(t==0) bsum[b] = red[0];
}

__global__ __launch_bounds__(256) void k_scanB(const int* __restrict__ bsum, int* __restrict__ bpre){
  __shared__ int sh[256];
  int t = threadIdx.x;
  for(int dir=0; dir<2; dir++){
    sh[t] = (t < NBLK)? bsum[dir*NBLK + t] : 0;
    __syncthreads();
    for(int d=1; d<256; d<<=1){
      int v = (t>=d)? sh[t-d] : 0;
      __syncthreads();
      sh[t] += v;
      __syncthreads();
    }
    if(t < NBLK) bpre[dir*NBLK + t] = (t==0)? 0 : sh[t-1];
    __syncthreads();
  }
}

__global__ __launch_bounds__(256) void k_scanC(const int* __restrict__ cnt_to,
      const int* __restrict__ cnt_from, const int* __restrict__ bpre,
      int* __restrict__ off_to, int* __restrict__ end_to,
      int* __restrict__ off_from, int* __restrict__ end_from){
  int b = blockIdx.x; int dir = (b >= NBLK); int bb = dir? b-NBLK : b;
  const int* cnt = dir? cnt_from : cnt_to;
  int* off = dir? off_from : off_to;
  int* end = dir? end_from : end_to;
  int t = threadIdx.x;
  int idx = bb*256 + t;
  int c = (idx < NNODES)? cnt[idx] : 0;
  __shared__ int sh[256];
  sh[t] = c; __syncthreads();
  for(int d=1; d<256; d<<=1){
    int v = (t>=d)? sh[t-d] : 0;
    __syncthreads();
    sh[t] += v;
    __syncthreads();
  }
  if(idx < NNODES){
    int o = bpre[b] + ((t==0)? 0 : sh[t-1]);
    off[idx] = o;
    end[idx] = o + c;
  }
}

__global__ void k_place(const int* __restrict__ i_link, const int* __restrict__ i_from,
                        const int* __restrict__ i_to,
                        const int* __restrict__ off_to, const int* __restrict__ off_from,
                        const int* __restrict__ rank_to, const int* __restrict__ rank_from,
                        int* __restrict__ pay_to, int* __restrict__ pay_from){
  int e = blockIdx.x*256 + threadIdx.x;
  if(e >= NEDGES) return;
  int il = i_link[e], f = i_from[e], tt = i_to[e];
  pay_to[off_to[tt] + rank_to[e]]   = f  | (il<<16);
  pay_from[off_from[f] + rank_from[e]] = tt | (il<<16);
}

// ---------------- gathers ----------------
__global__ __launch_bounds__(256) void k_gather_xin(const int* __restrict__ off, const int* __restrict__ end,
      const int* __restrict__ pay, const unsigned short* __restrict__ lp,
      const unsigned short* __restrict__ npart, unsigned short* __restrict__ out){
  int n = blockIdx.x*8 + (threadIdx.x>>5);
  if(n >= NNODES) return;
  int c = (threadIdx.x & 31)*4;
  float4 acc = make_float4(0.f,0.f,0.f,0.f);
  int s = off[n], e = end[n];
  for(int j=s;j<e;j++){
    int p = pay[j];
    int src = p & 0xFFFF, il = p >> 16;
    u16x4 a = *(const u16x4*)(lp + il*128 + c);
    u16x4 b = *(const u16x4*)(npart + (size_t)src*128 + c);
    acc.x += tanh_f(b2f(a[0])+b2f(b[0])); acc.y += tanh_f(b2f(a[1])+b2f(b[1]));
    acc.z += tanh_f(b2f(a[2])+b2f(b[2])); acc.w += tanh_f(b2f(a[3])+b2f(b[3]));
  }
  u16x4 o; o[0]=f2b(acc.x); o[1]=f2b(acc.y); o[2]=f2b(acc.z); o[3]=f2b(acc.w);
  *(u16x4*)(out + (size_t)n*128 + c) = o;
}

__global__ __launch_bounds__(256) void k_gather_xout(const int* __restrict__ off, const int* __restrict__ end,
      const int* __restrict__ pay, const unsigned short* __restrict__ lp,
      const unsigned short* __restrict__ npart, unsigned short* __restrict__ out){
  int n = blockIdx.x*8 + (threadIdx.x>>5);
  if(n >= NNODES) return;
  int c = (threadIdx.x & 31)*4;
  u16x4 bb = *(const u16x4*)(npart + (size_t)n*128 + c);
  float b0=b2f(bb[0]), b1=b2f(bb[1]), b2=b2f(bb[2]), b3=b2f(bb[3]);
  float4 acc = make_float4(0.f,0.f,0.f,0.f);
  int s = off[n], e = end[n];
  for(int j=s;j<e;j++){
    int p = pay[j];
    int il = p >> 16;
    u16x4 a = *(const u16x4*)(lp + il*128 + c);
    acc.x += tanh_f(b2f(a[0])+b0); acc.y += tanh_f(b2f(a[1])+b1);
    acc.z += tanh_f(b2f(a[2])+b2); acc.w += tanh_f(b2f(a[3])+b3);
  }
  u16x4 o; o[0]=f2b(acc.x); o[1]=f2b(acc.y); o[2]=f2b(acc.z); o[3]=f2b(acc.w);
  *(u16x4*)(out + (size_t)n*128 + c) = o;
}

__global__ __launch_bounds__(256) void k_gather_sum(const int* __restrict__ off, const int* __restrict__ end,
      const int* __restrict__ pay, const unsigned short* __restrict__ src, unsigned short* __restrict__ out){
  int n = blockIdx.x*8 + (threadIdx.x>>5);
  if(n >= NNODES) return;
  int c = (threadIdx.x & 31)*4;
  float s0=0.f,s1=0.f,s2=0.f,s3=0.f;
  int s = off[n], e = end[n];
  for(int j=s;j<e;j++){
    int v = pay[j] & 0xFFFF;
    u16x4 a = *(const u16x4*)(src + (size_t)v*128 + c);
    s0 += b2f(a[0]); s1 += b2f(a[1]); s2 += b2f(a[2]); s3 += b2f(a[3]);
  }
  u16x4 o; o[0]=f2b(s0); o[1]=f2b(s1); o[2]=f2b(s2); o[3]=f2b(s3);
  *(u16x4*)(out + (size_t)n*128 + c) = o;
}

// ---------------- fused MFMA gate GEMM + LSTM cell ----------------
// B from fragment-major Wfrag (coalesced 16B/lane), A staged in LDS (stride 36)
template<int P>
__global__ __launch_bounds__(256,2) void k_gates(
    const unsigned short* __restrict__ x0, const unsigned short* __restrict__ x1,
    const unsigned short* __restrict__ x2, const unsigned short* __restrict__ x3,
    const unsigned short* __restrict__ Wfrag,
    const float* __restrict__ bi, const float* __restrict__ bo,
    const float* __restrict__ bfg, const float* __restrict__ bu,
    float* __restrict__ cbuf, unsigned short* __restrict__ h1,
    float* __restrict__ hout)
{
  __shared__ unsigned short As[64*36];
  int t = threadIdx.x;
  int m0 = blockIdx.x*64;
  int w = t>>6; int l = t&63;
  int lm = l&15, kb = l>>4;
  f32x4 acc[2][4][4];
  #pragma unroll
  for(int a=0;a<2;a++)
    #pragma unroll
    for(int g=0;g<4;g++)
      #pragma unroll
      for(int r=0;r<4;r++) acc[a][g][r]=(f32x4){0.f,0.f,0.f,0.f};
  int sr = t>>2, sp = t&3;
  int sm = m0 + sr; if(sm >= NNODES) sm = NNODES-1;
  size_t soff = (size_t)sm*128 + sp*8;
  const int KSTEPS = P*4;
  for(int ks=0; ks<KSTEPS; ks++){
    const unsigned short* src;
    if(P==2) src = (ks<4)? x0 : x1;
    else     src = (ks<4)? x0 : (ks<8)? x1 : (ks<12)? x2 : x3;
    int d0 = (ks&3)*32;
    u16x8 v = *(const u16x8*)(src + soff + d0);
    *(u16x8*)(As + sr*36 + sp*8) = v;
    __syncthreads();
    s16x8 af[4];
    #pragma unroll
    for(int rt=0; rt<4; rt++)
      af[rt] = *(const s16x8*)(As + (16*rt+lm)*36 + kb*8);
    #pragma unroll
    for(int c=0;c<2;c++){
      #pragma unroll
      for(int g=0;g<4;g++){
        int nt = 8*g + 2*w + c;
        s16x8 bfr = *(const s16x8*)(Wfrag + (size_t)((ks*32 + nt)*64 + l)*8);
        #pragma unroll
        for(int rt=0; rt<4; rt++)
          acc[c][g][rt] = __builtin_amdgcn_mfma_f32_16x16x32_bf16(af[rt], bfr, acc[c][g][rt], 0,0,0);
      }
    }
    __syncthreads();
  }
  #pragma unroll
  for(int c=0;c<2;c++){
    int d = 16*(2*w+c) + lm;
    float vbi = bi[d], vbo = bo[d], vbu = bu[d];
    float vbf = (P==4)? bfg[d] : 0.f;
    #pragma unroll
    for(int rt=0; rt<4; rt++){
      #pragma unroll
      for(int reg=0; reg<4; reg++){
        int m = m0 + 16*rt + kb*4 + reg;
        if(m < NNODES){
          size_t o = (size_t)m*128 + d;
          float pi = acc[c][0][rt][reg] + vbi;
          float po = acc[c][1][rt][reg] + vbo;
          float pu = acc[c][3][rt][reg] + vbu;
          if(P==2){
            float c1v = sigf(pi)*tanh_f(pu);
            float hv  = sigf(po)*tanh_f(c1v);
            cbuf[o] = c1v;
            h1[o] = f2b(hv);
          } else {
            float pf = acc[c][2][rt][reg] + vbf;
            float c2 = sigf(pf)*cbuf[o] + sigf(pi)*tanh_f(pu);
            hout[o] = sigf(po)*tanh_f(c2);
          }
        }
      }
    }
  }
}

extern "C" void kernel_launch(void* const* d_in, const int* in_sizes, int n_in,
                              void* d_out, int out_size, void* d_ws, size_t ws_size,
                              hipStream_t stream){
  const int*   i_token  = (const int*)d_in[0];
  const int*   i_link   = (const int*)d_in[1];
  const int*   i_from   = (const int*)d_in[2];
  const int*   i_to     = (const int*)d_in[3];
  const float* emb_token= (const float*)d_in[4];
  const float* emb_link = (const float*)d_in[5];
  const float* Wc = (const float*)d_in[6];  const float* bc = (const float*)d_in[7];
  const float* Wl = (const float*)d_in[8];  const float* bl = (const float*)d_in[9];
  const float* Wi = (const float*)d_in[10]; const float* bi = (const float*)d_in[11];
  const float* Wo = (const float*)d_in[12]; const float* bo = (const float*)d_in[13];
  const float* Wf = (const float*)d_in[14]; const float* bf_ = (const float*)d_in[15];
  const float* Wu = (const float*)d_in[16]; const float* bu = (const float*)d_in[17];
  float* out = (float*)d_out;

  const size_t NB = (size_t)NNODES*128;
  float* bufA   = (float*)d_ws;            // node_emb (fp32)
  float* c1buf  = bufA + NB;
  unsigned short* npart = (unsigned short*)(c1buf + NB);
  unsigned short* xin   = npart + NB;
  unsigned short* xout  = xin + NB;
  unsigned short* hin   = xout + NB;
  unsigned short* houtb = hin + NB;
  unsigned short* h1    = houtb + NB;
  unsigned short* WgT   = h1 + NB;
  unsigned short* linkpart = WgT + 512*512;
  int* ia = (int*)(linkpart + 50*128);
  int* cnt_to   = ia + 0*NNODES;
  int* cnt_from = ia + 1*NNODES;
  int* off_to   = ia + 2*NNODES;
  int* end_to   = ia + 3*NNODES;
  int* off_from = ia + 4*NNODES;
  int* end_from = ia + 5*NNODES;
  int* bsum     = ia + 6*NNODES;
  int* bpre     = bsum + 2*NBLK;
  int* pay_to   = bpre + 2*NBLK;
  int* pay_from = pay_to + NEDGES;
  int* rank_to  = pay_from + NEDGES;
  int* rank_from= rank_to + NEDGES;

  const int GB = (NNODES + 63)/64;   // 782
  const int GE = (NEDGES + 255)/256; // 3125
  const int GN = (NNODES + 7)/8;     // 6250

  // CSR build: 1 atomic pass + parallel scan + non-atomic place
  hipMemsetAsync(cnt_to, 0, 2*NNODES*sizeof(int), stream);
  k_hist<<<GE,256,0,stream>>>(i_to, i_from, cnt_to, cnt_from, rank_to, rank_from);
  k_scanA<<<2*NBLK,256,0,stream>>>(cnt_to, cnt_from, bsum);
  k_scanB<<<1,256,0,stream>>>(bsum, bpre);
  k_scanC<<<2*NBLK,256,0,stream>>>(cnt_to, cnt_from, bpre, off_to, end_to, off_from, end_from);
  k_place<<<GE,256,0,stream>>>(i_link, i_from, i_to, off_to, off_from,
                               rank_to, rank_from, pay_to, pay_from);

  // weights + node features
  k_prepw<<<512,512,0,stream>>>(Wi, Wo, Wf, Wu, WgT);
  k_linkpart<<<50,128,0,stream>>>(emb_link, Wl, bl, linkpart);
  k_node_emb<<<GB,256,0,stream>>>(i_token, emb_token, Wc, bc, bufA);
  k_gemm1<<<GB,256,0,stream>>>(bufA, Wl + 64*128, npart);

  // x gathers -> bf16
  k_gather_xin <<<GN,256,0,stream>>>(off_to,  end_to,  pay_to,  linkpart, npart, xin);
  k_gather_xout<<<GN,256,0,stream>>>(off_from,end_from,pay_from,linkpart, npart, xout);

  // layer 1 fused
  k_gates<2><<<GB,256,0,stream>>>(xin, xout, nullptr, nullptr, WgT,
                                  bi, bo, bf_, bu, c1buf, h1, nullptr);

  // h gathers -> bf16
  k_gather_sum<<<GN,256,0,stream>>>(off_to,  end_to,  pay_to,  h1, hin);
  k_gather_sum<<<GN,256,0,stream>>>(off_from,end_from,pay_from,h1, houtb);

  // layer 2 fused
  k_gates<4><<<GB,256,0,stream>>>(xin, xout, hin, houtb, WgT,
                                  bi, bo, bf_, bu, c1buf, nullptr, out);
}

// Round 6
// 411.584 us; speedup vs baseline: 15.0223x; 1.4612x over previous
//
#include <hip/hip_runtime.h>
#include <math.h>

#define NNODES 50000
#define NEDGES 800000
#define NBLK 196   // ceil(50000/256)

typedef __attribute__((ext_vector_type(8))) short s16x8;
typedef __attribute__((ext_vector_type(8))) unsigned short u16x8;
typedef __attribute__((ext_vector_type(4))) unsigned short u16x4;
typedef __attribute__((ext_vector_type(4))) float f32x4;

__device__ __forceinline__ float tanh_fast(float x){
  float e = __builtin_amdgcn_exp2f(x*2.885390081777927f);   // e^(2x)
  return 1.0f - 2.0f*__builtin_amdgcn_rcpf(e+1.0f);
}
__device__ __forceinline__ float sig_fast(float x){
  float e = __builtin_amdgcn_exp2f(-1.4426950408889634f*x); // e^(-x)
  return __builtin_amdgcn_rcpf(1.0f+e);
}
__device__ __forceinline__ unsigned short f2b(float f){
  union{float f; unsigned u;} v; v.f = f;
  unsigned r = (v.u + 0x7FFFu + ((v.u>>16)&1u)) >> 16;
  return (unsigned short)r;
}
__device__ __forceinline__ float b2f(unsigned short b){
  union{unsigned u; float f;} v; v.u = ((unsigned)b)<<16; return v.f;
}

// linkpart[l][d] = bf16(bl[d] + sum_k emb_link[l][k]*Wl[k][d])
__global__ void k_linkpart(const float* __restrict__ emb_link, const float* __restrict__ Wl,
                           const float* __restrict__ bl, unsigned short* __restrict__ lp){
  int l = blockIdx.x, d = threadIdx.x;
  float acc = bl[d];
  #pragma unroll 8
  for(int k=0;k<64;k++) acc += emb_link[l*64+k]*Wl[k*128+d];
  lp[l*128+d] = f2b(acc);
}

// Fragment-major gate weights (K=512):
// Wfrag[((ks*32 + nt)*64 + l)*8 + j],  n = nt*16+(l&15), k = ks*32+(l>>4)*8+j
__global__ void k_prepw(const float* __restrict__ Wi, const float* __restrict__ Wo,
                        const float* __restrict__ Wf, const float* __restrict__ Wu,
                        unsigned short* __restrict__ Wfrag){
  int n = blockIdx.x; int k = threadIdx.x;
  const float* W = (n<128)? Wi : (n<256)? Wo : (n<384)? Wf : Wu;
  float v = W[(size_t)k*128 + (n&127)];
  int ks = k>>5, kb = (k>>3)&3, j = k&7;
  int nt = n>>4, lm = n&15;
  int l = lm + 16*kb;
  Wfrag[(size_t)(((ks*32 + nt)*64) + l)*8 + j] = f2b(v);
}

// Wcfrag: K=320 (Wc is 300 rows, zero-pad), N=128
__global__ void k_prepw_c(const float* __restrict__ Wc, unsigned short* __restrict__ Wcfrag){
  int n = blockIdx.x; int k = threadIdx.x;   // n<128, k<320
  float v = (k < 300)? Wc[(size_t)k*128 + n] : 0.f;
  int ks = k>>5, kb = (k>>3)&3, j = k&7;
  int nt = n>>4, lm = n&15;
  int l = lm + 16*kb;
  Wcfrag[(size_t)(((ks*8 + nt)*64) + l)*8 + j] = f2b(v);
}

// Wlfrag: bottom 128 rows of Wl, N=128
__global__ void k_prepw_l(const float* __restrict__ Wl, unsigned short* __restrict__ Wlfrag){
  int n = blockIdx.x; int k = threadIdx.x;   // n<128, k<128
  float v = Wl[(size_t)(64+k)*128 + n];
  int ks = k>>5, kb = (k>>3)&3, j = k&7;
  int nt = n>>4, lm = n&15;
  int l = lm + 16*kb;
  Wlfrag[(size_t)(((ks*8 + nt)*64) + l)*8 + j] = f2b(v);
}

// Fused: E1 = tanh(gather(emb_token)@Wc + bc); npart = bf16(E1 @ Wl[64:192])
__global__ __launch_bounds__(256,2) void k_ne(const int* __restrict__ i_token,
      const float* __restrict__ emb_token, const unsigned short* __restrict__ Wcfrag,
      const float* __restrict__ bc, const unsigned short* __restrict__ Wlfrag,
      unsigned short* __restrict__ npart){
  __shared__ unsigned short As[64*36];
  __shared__ unsigned short E1[64*132];
  __shared__ int rowidx[64];
  int t = threadIdx.x;
  int m0 = blockIdx.x*64;
  if(t<64){ int m=m0+t; rowidx[t]=(m<NNODES)? i_token[m]:0; }
  int w=t>>6, l=t&63, lm=l&15, kb=l>>4;
  f32x4 acc[2][4];
  #pragma unroll
  for(int c=0;c<2;c++)
    #pragma unroll
    for(int r=0;r<4;r++) acc[c][r]=(f32x4){0.f,0.f,0.f,0.f};
  int sr=t>>2, sp=t&3;
  __syncthreads();
  const float* srcrow = emb_token + (size_t)rowidx[sr]*300;
  for(int ks=0; ks<10; ks++){
    int k0 = ks*32 + sp*8;
    u16x8 v;
    #pragma unroll
    for(int j=0;j<8;j++){ int k=k0+j; v[j] = (k<300)? f2b(srcrow[k]) : (unsigned short)0; }
    if(ks) __syncthreads();
    *(u16x8*)(As + sr*36 + sp*8) = v;
    __syncthreads();
    s16x8 af[4];
    #pragma unroll
    for(int rt=0;rt<4;rt++) af[rt] = *(const s16x8*)(As + (16*rt+lm)*36 + kb*8);
    #pragma unroll
    for(int c=0;c<2;c++){
      int nt = 2*w + c;
      s16x8 bfr = *(const s16x8*)(Wcfrag + (size_t)((ks*8+nt)*64 + l)*8);
      #pragma unroll
      for(int rt=0;rt<4;rt++)
        acc[c][rt] = __builtin_amdgcn_mfma_f32_16x16x32_bf16(af[rt], bfr, acc[c][rt],0,0,0);
    }
  }
  __syncthreads();
  #pragma unroll
  for(int c=0;c<2;c++){
    int d = 16*(2*w+c) + lm;
    float vb = bc[d];
    #pragma unroll
    for(int rt=0;rt<4;rt++)
      #pragma unroll
      for(int reg=0;reg<4;reg++){
        int r = 16*rt + kb*4 + reg;
        E1[r*132 + d] = f2b(tanh_fast(acc[c][rt][reg]+vb));
      }
  }
  __syncthreads();
  f32x4 acc2[2][4];
  #pragma unroll
  for(int c=0;c<2;c++)
    #pragma unroll
    for(int r=0;r<4;r++) acc2[c][r]=(f32x4){0.f,0.f,0.f,0.f};
  #pragma unroll
  for(int ks=0; ks<4; ks++){
    s16x8 af[4];
    #pragma unroll
    for(int rt=0;rt<4;rt++) af[rt] = *(const s16x8*)(E1 + (16*rt+lm)*132 + ks*32 + kb*8);
    #pragma unroll
    for(int c=0;c<2;c++){
      int nt = 2*w + c;
      s16x8 bfr = *(const s16x8*)(Wlfrag + (size_t)((ks*8+nt)*64 + l)*8);
      #pragma unroll
      for(int rt=0;rt<4;rt++)
        acc2[c][rt] = __builtin_amdgcn_mfma_f32_16x16x32_bf16(af[rt], bfr, acc2[c][rt],0,0,0);
    }
  }
  #pragma unroll
  for(int c=0;c<2;c++){
    int d = 16*(2*w+c) + lm;
    #pragma unroll
    for(int rt=0;rt<4;rt++)
      #pragma unroll
      for(int reg=0;reg<4;reg++){
        int m = m0 + 16*rt + kb*4 + reg;
        if(m < NNODES) npart[(size_t)m*128 + d] = f2b(acc2[c][rt][reg]);
      }
  }
}

// ---------------- CSR build ----------------
__global__ void k_hist(const int* __restrict__ i_to, const int* __restrict__ i_from,
                       int* __restrict__ cnt_to, int* __restrict__ cnt_from,
                       int* __restrict__ rank_to, int* __restrict__ rank_from){
  int e = blockIdx.x*256 + threadIdx.x;
  if(e >= NEDGES) return;
  rank_to[e]   = atomicAdd(&cnt_to[i_to[e]], 1);
  rank_from[e] = atomicAdd(&cnt_from[i_from[e]], 1);
}

__global__ __launch_bounds__(256) void k_scanA(const int* __restrict__ cnt_to,
      const int* __restrict__ cnt_from, int* __restrict__ bsum){
  int b = blockIdx.x; int dir = (b >= NBLK); int bb = dir? b-NBLK : b;
  const int* cnt = dir? cnt_from : cnt_to;
  int t = threadIdx.x;
  int idx = bb*256 + t;
  int c = (idx < NNODES)? cnt[idx] : 0;
  __shared__ int red[256];
  red[t] = c; __syncthreads();
  for(int s=128;s>0;s>>=1){ if(t<s) red[t]+=red[t+s]; __syncthreads(); }
  if(t==0) bsum[b] = red[0];
}

__global__ __launch_bounds__(256) void k_scanB(const int* __restrict__ bsum, int* __restrict__ bpre){
  __shared__ int sh[256];
  int t = threadIdx.x;
  for(int dir=0; dir<2; dir++){
    sh[t] = (t < NBLK)? bsum[dir*NBLK + t] : 0;
    __syncthreads();
    for(int d=1; d<256; d<<=1){
      int v = (t>=d)? sh[t-d] : 0;
      __syncthreads();
      sh[t] += v;
      __syncthreads();
    }
    if(t < NBLK) bpre[dir*NBLK + t] = (t==0)? 0 : sh[t-1];
    __syncthreads();
  }
}

__global__ __launch_bounds__(256) void k_scanC(const int* __restrict__ cnt_to,
      const int* __restrict__ cnt_from, const int* __restrict__ bpre,
      int* __restrict__ off_to, int* __restrict__ end_to,
      int* __restrict__ off_from, int* __restrict__ end_from){
  int b = blockIdx.x; int dir = (b >= NBLK); int bb = dir? b-NBLK : b;
  const int* cnt = dir? cnt_from : cnt_to;
  int* off = dir? off_from : off_to;
  int* end = dir? end_from : end_to;
  int t = threadIdx.x;
  int idx = bb*256 + t;
  int c = (idx < NNODES)? cnt[idx] : 0;
  __shared__ int sh[256];
  sh[t] = c; __syncthreads();
  for(int d=1; d<256; d<<=1){
    int v = (t>=d)? sh[t-d] : 0;
    __syncthreads();
    sh[t] += v;
    __syncthreads();
  }
  if(idx < NNODES){
    int o = bpre[b] + ((t==0)? 0 : sh[t-1]);
    off[idx] = o;
    end[idx] = o + c;
  }
}

__global__ void k_place(const int* __restrict__ i_link, const int* __restrict__ i_from,
                        const int* __restrict__ i_to,
                        const int* __restrict__ off_to, const int* __restrict__ off_from,
                        const int* __restrict__ rank_to, const int* __restrict__ rank_from,
                        int* __restrict__ pay_to, int* __restrict__ pay_from){
  int e = blockIdx.x*256 + threadIdx.x;
  if(e >= NEDGES) return;
  int il = i_link[e], f = i_from[e], tt = i_to[e];
  pay_to[off_to[tt] + rank_to[e]]   = f  | (il<<16);
  pay_from[off_from[f] + rank_from[e]] = tt | (il<<16);
}

// ---------------- gathers (16 lanes per node, u16x8 = 16B per lane) ----------------
__global__ __launch_bounds__(256) void k_gather_xin(const int* __restrict__ off, const int* __restrict__ end,
      const int* __restrict__ pay, const unsigned short* __restrict__ lp,
      const unsigned short* __restrict__ npart, unsigned short* __restrict__ out){
  int n = blockIdx.x*16 + (threadIdx.x>>4);
  if(n >= NNODES) return;
  int c = (threadIdx.x & 15)*8;
  float acc[8];
  #pragma unroll
  for(int q=0;q<8;q++) acc[q]=0.f;
  int s = off[n], e = end[n];
  for(int j=s;j<e;j++){
    int p = pay[j];
    int src = p & 0xFFFF, il = p >> 16;
    u16x8 a = *(const u16x8*)(lp + il*128 + c);
    u16x8 b = *(const u16x8*)(npart + (size_t)src*128 + c);
    #pragma unroll
    for(int q=0;q<8;q++) acc[q] += tanh_fast(b2f(a[q])+b2f(b[q]));
  }
  u16x8 o;
  #pragma unroll
  for(int q=0;q<8;q++) o[q]=f2b(acc[q]);
  *(u16x8*)(out + (size_t)n*128 + c) = o;
}

__global__ __launch_bounds__(256) void k_gather_xout(const int* __restrict__ off, const int* __restrict__ end,
      const int* __restrict__ pay, const unsigned short* __restrict__ lp,
      const unsigned short* __restrict__ npart, unsigned short* __restrict__ out){
  int n = blockIdx.x*16 + (threadIdx.x>>4);
  if(n >= NNODES) return;
  int c = (threadIdx.x & 15)*8;
  u16x8 bb = *(const u16x8*)(npart + (size_t)n*128 + c);
  float bf[8];
  #pragma unroll
  for(int q=0;q<8;q++) bf[q]=b2f(bb[q]);
  float acc[8];
  #pragma unroll
  for(int q=0;q<8;q++) acc[q]=0.f;
  int s = off[n], e = end[n];
  for(int j=s;j<e;j++){
    int il = pay[j] >> 16;
    u16x8 a = *(const u16x8*)(lp + il*128 + c);
    #pragma unroll
    for(int q=0;q<8;q++) acc[q] += tanh_fast(b2f(a[q])+bf[q]);
  }
  u16x8 o;
  #pragma unroll
  for(int q=0;q<8;q++) o[q]=f2b(acc[q]);
  *(u16x8*)(out + (size_t)n*128 + c) = o;
}

__global__ __launch_bounds__(256) void k_gather_sum(const int* __restrict__ off, const int* __restrict__ end,
      const int* __restrict__ pay, const unsigned short* __restrict__ src, unsigned short* __restrict__ out){
  int n = blockIdx.x*16 + (threadIdx.x>>4);
  if(n >= NNODES) return;
  int c = (threadIdx.x & 15)*8;
  float acc[8];
  #pragma unroll
  for(int q=0;q<8;q++) acc[q]=0.f;
  int s = off[n], e = end[n];
  for(int j=s;j<e;j++){
    int v = pay[j] & 0xFFFF;
    u16x8 a = *(const u16x8*)(src + (size_t)v*128 + c);
    #pragma unroll
    for(int q=0;q<8;q++) acc[q] += b2f(a[q]);
  }
  u16x8 o;
  #pragma unroll
  for(int q=0;q<8;q++) o[q]=f2b(acc[q]);
  *(u16x8*)(out + (size_t)n*128 + c) = o;
}

// ---------------- fused MFMA gate GEMM + LSTM cell ----------------
template<int P>
__global__ __launch_bounds__(256,2) void k_gates(
    const unsigned short* __restrict__ x0, const unsigned short* __restrict__ x1,
    const unsigned short* __restrict__ x2, const unsigned short* __restrict__ x3,
    const unsigned short* __restrict__ Wfrag,
    const float* __restrict__ bi, const float* __restrict__ bo,
    const float* __restrict__ bfg, const float* __restrict__ bu,
    float* __restrict__ cbuf, unsigned short* __restrict__ h1,
    float* __restrict__ hout)
{
  __shared__ unsigned short As[64*36];
  int t = threadIdx.x;
  int m0 = blockIdx.x*64;
  int w = t>>6; int l = t&63;
  int lm = l&15, kb = l>>4;
  f32x4 acc[2][4][4];
  #pragma unroll
  for(int a=0;a<2;a++)
    #pragma unroll
    for(int g=0;g<4;g++)
      #pragma unroll
      for(int r=0;r<4;r++) acc[a][g][r]=(f32x4){0.f,0.f,0.f,0.f};
  int sr = t>>2, sp = t&3;
  int sm = m0 + sr; if(sm >= NNODES) sm = NNODES-1;
  size_t soff = (size_t)sm*128 + sp*8;
  const int KSTEPS = P*4;
  for(int ks=0; ks<KSTEPS; ks++){
    const unsigned short* src;
    if(P==2) src = (ks<4)? x0 : x1;
    else     src = (ks<4)? x0 : (ks<8)? x1 : (ks<12)? x2 : x3;
    int d0 = (ks&3)*32;
    u16x8 v = *(const u16x8*)(src + soff + d0);
    *(u16x8*)(As + sr*36 + sp*8) = v;
    __syncthreads();
    s16x8 af[4];
    #pragma unroll
    for(int rt=0; rt<4; rt++)
      af[rt] = *(const s16x8*)(As + (16*rt+lm)*36 + kb*8);
    #pragma unroll
    for(int c=0;c<2;c++){
      #pragma unroll
      for(int g=0;g<4;g++){
        int nt = 8*g + 2*w + c;
        s16x8 bfr = *(const s16x8*)(Wfrag + (size_t)((ks*32 + nt)*64 + l)*8);
        #pragma unroll
        for(int rt=0; rt<4; rt++)
          acc[c][g][rt] = __builtin_amdgcn_mfma_f32_16x16x32_bf16(af[rt], bfr, acc[c][g][rt], 0,0,0);
      }
    }
    __syncthreads();
  }
  #pragma unroll
  for(int c=0;c<2;c++){
    int d = 16*(2*w+c) + lm;
    float vbi = bi[d], vbo = bo[d], vbu = bu[d];
    float vbf = (P==4)? bfg[d] : 0.f;
    #pragma unroll
    for(int rt=0; rt<4; rt++){
      #pragma unroll
      for(int reg=0; reg<4; reg++){
        int m = m0 + 16*rt + kb*4 + reg;
        if(m < NNODES){
          size_t o = (size_t)m*128 + d;
          float pi = acc[c][0][rt][reg] + vbi;
          float po = acc[c][1][rt][reg] + vbo;
          float pu = acc[c][3][rt][reg] + vbu;
          if(P==2){
            float c1v = sig_fast(pi)*tanh_fast(pu);
            float hv  = sig_fast(po)*tanh_fast(c1v);
            cbuf[o] = c1v;
            h1[o] = f2b(hv);
          } else {
            float pf = acc[c][2][rt][reg] + vbf;
            float c2 = sig_fast(pf)*cbuf[o] + sig_fast(pi)*tanh_fast(pu);
            hout[o] = sig_fast(po)*tanh_fast(c2);
          }
        }
      }
    }
  }
}

extern "C" void kernel_launch(void* const* d_in, const int* in_sizes, int n_in,
                              void* d_out, int out_size, void* d_ws, size_t ws_size,
                              hipStream_t stream){
  const int*   i_token  = (const int*)d_in[0];
  const int*   i_link   = (const int*)d_in[1];
  const int*   i_from   = (const int*)d_in[2];
  const int*   i_to     = (const int*)d_in[3];
  const float* emb_token= (const float*)d_in[4];
  const float* emb_link = (const float*)d_in[5];
  const float* Wc = (const float*)d_in[6];  const float* bc = (const float*)d_in[7];
  const float* Wl = (const float*)d_in[8];  const float* bl = (const float*)d_in[9];
  const float* Wi = (const float*)d_in[10]; const float* bi = (const float*)d_in[11];
  const float* Wo = (const float*)d_in[12]; const float* bo = (const float*)d_in[13];
  const float* Wf = (const float*)d_in[14]; const float* bf_ = (const float*)d_in[15];
  const float* Wu = (const float*)d_in[16]; const float* bu = (const float*)d_in[17];
  float* out = (float*)d_out;

  const size_t NB = (size_t)NNODES*128;
  float* c1buf  = (float*)d_ws;
  unsigned short* npart = (unsigned short*)(c1buf + NB);
  unsigned short* xin   = npart + NB;
  unsigned short* xout  = xin + NB;
  unsigned short* hin   = xout + NB;
  unsigned short* houtb = hin + NB;
  unsigned short* h1    = houtb + NB;
  unsigned short* WgT   = h1 + NB;
  unsigned short* Wcfrag = WgT + 512*512;
  unsigned short* Wlfrag = Wcfrag + 320*128;
  unsigned short* linkpart = Wlfrag + 128*128;
  int* ia = (int*)(linkpart + 50*128);
  int* cnt_to   = ia + 0*NNODES;
  int* cnt_from = ia + 1*NNODES;
  int* off_to   = ia + 2*NNODES;
  int* end_to   = ia + 3*NNODES;
  int* off_from = ia + 4*NNODES;
  int* end_from = ia + 5*NNODES;
  int* bsum     = ia + 6*NNODES;
  int* bpre     = bsum + 2*NBLK;
  int* pay_to   = bpre + 2*NBLK;
  int* pay_from = pay_to + NEDGES;
  int* rank_to  = pay_from + NEDGES;
  int* rank_from= rank_to + NEDGES;

  const int GB = (NNODES + 63)/64;    // 782
  const int GE = (NEDGES + 255)/256;  // 3125
  const int GN = (NNODES + 15)/16;    // 3125 (16-lane gathers)

  // CSR build: 1 atomic pass + parallel scan + non-atomic place
  hipMemsetAsync(cnt_to, 0, 2*NNODES*sizeof(int), stream);
  k_hist<<<GE,256,0,stream>>>(i_to, i_from, cnt_to, cnt_from, rank_to, rank_from);
  k_scanA<<<2*NBLK,256,0,stream>>>(cnt_to, cnt_from, bsum);
  k_scanB<<<1,256,0,stream>>>(bsum, bpre);
  k_scanC<<<2*NBLK,256,0,stream>>>(cnt_to, cnt_from, bpre, off_to, end_to, off_from, end_from);
  k_place<<<GE,256,0,stream>>>(i_link, i_from, i_to, off_to, off_from,
                               rank_to, rank_from, pay_to, pay_from);

  // weight prepacks + node features
  k_prepw<<<512,512,0,stream>>>(Wi, Wo, Wf, Wu, WgT);
  k_prepw_c<<<128,320,0,stream>>>(Wc, Wcfrag);
  k_prepw_l<<<128,128,0,stream>>>(Wl, Wlfrag);
  k_linkpart<<<50,128,0,stream>>>(emb_link, Wl, bl, linkpart);
  k_ne<<<GB,256,0,stream>>>(i_token, emb_token, Wcfrag, bc, Wlfrag, npart);

  // x gathers -> bf16
  k_gather_xin <<<GN,256,0,stream>>>(off_to,  end_to,  pay_to,  linkpart, npart, xin);
  k_gather_xout<<<GN,256,0,stream>>>(off_from,end_from,pay_from,linkpart, npart, xout);

  // layer 1 fused
  k_gates<2><<<GB,256,0,stream>>>(xin, xout, nullptr, nullptr, WgT,
                                  bi, bo, bf_, bu, c1buf, h1, nullptr);

  // h gathers -> bf16
  k_gather_sum<<<GN,256,0,stream>>>(off_to,  end_to,  pay_to,  h1, hin);
  k_gather_sum<<<GN,256,0,stream>>>(off_from,end_from,pay_from,h1, houtb);

  // layer 2 fused
  k_gates<4><<<GB,256,0,stream>>>(xin, xout, hin, houtb, WgT,
                                  bi, bo, bf_, bu, c1buf, nullptr, out);
}